// Round 1
// 173.758 us; speedup vs baseline: 1.1141x; 1.1141x over previous
//
#include <hip/hip_runtime.h>

typedef unsigned short u16;
typedef unsigned int u32;
// may_alias: reinterpret-cast LDS/global vector access (prevent TBAA reorder).
typedef __attribute__((ext_vector_type(8), may_alias)) short short8;
typedef __attribute__((ext_vector_type(4), may_alias)) u32 uint4_ma;
typedef __attribute__((ext_vector_type(2), may_alias)) u32 uint2_ma;
typedef __attribute__((ext_vector_type(4), may_alias)) float floatx4_ma;
typedef __attribute__((ext_vector_type(4))) float floatx4;

#define DEV static __device__ __forceinline__

constexpr int S = 128, NRES = 256, D = 256, H = 8;
constexpr float ATT_SCALE = 0.17677669529663687f;  // 1/sqrt(32)

DEV u16 f2bf(float f) {
  union { float f; u32 u; } v; v.f = f;
  u32 u = v.u;
  return (u16)((u + 0x7fffu + ((u >> 16) & 1u)) >> 16);  // RNE
}

// wave-local LDS ordering: drains this wave's ds ops; full compiler memory
// barrier. Replaces __syncthreads where the LDS buffer is per-wave.
DEV void lds_fence() { asm volatile("s_waitcnt lgkmcnt(0)" ::: "memory"); }

// ---------------------------------------------------------------- LayerNorm
// f32 in, bf16 out. One wave per row of 256; float4/lane. ~roofline already.
__global__ __launch_bounds__(256) void ln_kernel(const float* __restrict__ x,
                                                 const float* __restrict__ w,
                                                 const float* __restrict__ b,
                                                 u16* __restrict__ xn) {
  const int lane = threadIdx.x & 63;
  const int row = blockIdx.x * 4 + (threadIdx.x >> 6);
  floatx4_ma d = ((const floatx4_ma*)(x + (size_t)row * D))[lane];
  float s = d[0] + d[1] + d[2] + d[3];
  float ss = d[0] * d[0] + d[1] * d[1] + d[2] * d[2] + d[3] * d[3];
#pragma unroll
  for (int off = 32; off > 0; off >>= 1) {
    s += __shfl_xor(s, off, 64);
    ss += __shfl_xor(ss, off, 64);
  }
  const float mean = s * (1.0f / D);
  const float var = ss * (1.0f / D) - mean * mean;
  const float rstd = rsqrtf(var + 1e-5f);
  floatx4_ma wd = ((const floatx4_ma*)w)[lane];
  floatx4_ma bd = ((const floatx4_ma*)b)[lane];
  uint2_ma o;
  o.x = (u32)f2bf((d[0] - mean) * rstd * wd[0] + bd[0]) |
        ((u32)f2bf((d[1] - mean) * rstd * wd[1] + bd[1]) << 16);
  o.y = (u32)f2bf((d[2] - mean) * rstd * wd[2] + bd[2]) |
        ((u32)f2bf((d[3] - mean) * rstd * wd[3] + bd[3]) << 16);
  ((uint2_ma*)(xn + (size_t)row * D))[lane] = o;
}

// ------------------------------------------------- weight pre-conversion
// f32 -> bf16 once per launch; removes per-block convert from every GEMM
// block (6144 of them). 1 MB read total.
__global__ __launch_bounds__(256) void wcvt_kernel(
    const float* __restrict__ w0, const float* __restrict__ w1,
    const float* __restrict__ w2, const float* __restrict__ w3,
    u16* __restrict__ wb) {
  const float* src = (blockIdx.y == 0) ? w0
                     : ((blockIdx.y == 1) ? w1 : ((blockIdx.y == 2) ? w2 : w3));
  u16* dst = wb + (size_t)blockIdx.y * 65536;
  const int i = (blockIdx.x * 256 + threadIdx.x) * 8;
  floatx4_ma f0 = *(const floatx4_ma*)(src + i);
  floatx4_ma f1 = *(const floatx4_ma*)(src + i + 4);
  short8 hv;
  hv[0] = (short)f2bf(f0[0]); hv[1] = (short)f2bf(f0[1]);
  hv[2] = (short)f2bf(f0[2]); hv[3] = (short)f2bf(f0[3]);
  hv[4] = (short)f2bf(f1[0]); hv[5] = (short)f2bf(f1[1]);
  hv[6] = (short)f2bf(f1[2]); hv[7] = (short)f2bf(f1[3]);
  *(short8*)(dst + i) = hv;
}

// ------------------------------------------------------- staging helper
// 64x64 bf16 tile via async DMA. LDS linear, global source pre-swizzled
// (granule g_l holds global granule g_l ^ (r&7)) so ds_read_b128 fragments
// are bank-conflict-free. src row stride = 256 elems.
DEV void stage64x64(const u16* src, u16* dst, int lane, int wv) {
#pragma unroll
  for (int it = 0; it < 2; ++it) {
    const int idx = wv * 2 + it;          // 8-row slab, wave-uniform LDS base
    const int r = idx * 8 + (lane >> 3);  // row 0..63
    const int g = lane & 7;               // linear granule 0..7
    const int gofs = r * 256 + ((g ^ (r & 7)) << 3);
    __builtin_amdgcn_global_load_lds(
        (const __attribute__((address_space(1))) u32*)(src + gofs),
        (__attribute__((address_space(3))) u32*)(dst + idx * 512), 16, 0, 0);
  }
}

// Shared 64x64 MFMA core over one BK=64 K-slab. OPERANDS SWAPPED
// (mfma(b,a)): output col index = A-row (m), row index = W-row (n), so each
// lane holds 4 consecutive n -> packed stores in the epilogue.
DEV void mfma_core64(const u16* As, const u16* Bs, int lane, int wv, floatx4 acc[2][2]) {
  const int wr = wv >> 1, wc = wv & 1;
  const int q4 = lane >> 4, r16 = lane & 15;
#pragma unroll
  for (int kk = 0; kk < 2; ++kk) {
    const int G = kk * 4 + q4;
    short8 a[2], b[2];
#pragma unroll
    for (int i = 0; i < 2; ++i) {
      const int mr = wr * 32 + i * 16 + r16;
      a[i] = *(const short8*)(As + mr * 64 + ((G ^ (mr & 7)) << 3));
      const int nr = wc * 32 + i * 16 + r16;
      b[i] = *(const short8*)(Bs + nr * 64 + ((G ^ (nr & 7)) << 3));
    }
#pragma unroll
    for (int i = 0; i < 2; ++i)
#pragma unroll
      for (int j = 0; j < 2; ++j)
        acc[i][j] = __builtin_amdgcn_mfma_f32_16x16x32_bf16(b[j], a[i], acc[i][j], 0, 0, 0);
  }
}

// 2-phase pipelined K-loop (T3 minimum): issue next slab's DMA, compute
// current, barrier. LDS = 32 KiB total -> 5 blocks/CU (was 64 KiB -> 2).
DEV void gemm_loop(const u16* Ab, const u16* Wb, u16 (*As)[4096], u16 (*Bs)[4096],
                   int lane, int wv, floatx4 acc[2][2]) {
  stage64x64(Ab, As[0], lane, wv);
  stage64x64(Wb, Bs[0], lane, wv);
  __syncthreads();
#pragma unroll
  for (int t = 0; t < 4; ++t) {
    const int cur = t & 1;
    if (t < 3) {
      stage64x64(Ab + (t + 1) * 64, As[cur ^ 1], lane, wv);
      stage64x64(Wb + (t + 1) * 64, Bs[cur ^ 1], lane, wv);
    }
    mfma_core64(As[cur], Bs[cur], lane, wv, acc);
    if (t < 3) __syncthreads();
  }
}

// ------------------------------------------------------------ QKV GEMM
__global__ __launch_bounds__(256) void gemm_qkv_kernel(
    const u16* __restrict__ A, const u16* __restrict__ wb,
    u16* __restrict__ C0, u16* __restrict__ C1, u16* __restrict__ C2) {
  alignas(16) __shared__ u16 As[2][64 * 64];
  alignas(16) __shared__ u16 Bs[2][64 * 64];
  const int tid = threadIdx.x, lane = tid & 63, wv = tid >> 6;
  const int m0 = blockIdx.x * 64, n0 = blockIdx.y * 64;
  const u16* Wp = wb + (size_t)blockIdx.z * 65536;
  u16* Cp = (blockIdx.z == 0) ? C0 : ((blockIdx.z == 1) ? C1 : C2);

  floatx4 acc[2][2] = {};
  gemm_loop(A + (size_t)m0 * 256, Wp + (size_t)n0 * 256, As, Bs, lane, wv, acc);

  const int wr = wv >> 1, wc = wv & 1, q4 = lane >> 4, r16 = lane & 15;
#pragma unroll
  for (int i = 0; i < 2; ++i) {
    const int m = m0 + wr * 32 + i * 16 + r16;
#pragma unroll
    for (int j = 0; j < 2; ++j) {
      const int n = n0 + wc * 32 + j * 16 + q4 * 4;
      uint2_ma o;
      o.x = (u32)f2bf(acc[i][j][0]) | ((u32)f2bf(acc[i][j][1]) << 16);
      o.y = (u32)f2bf(acc[i][j][2]) | ((u32)f2bf(acc[i][j][3]) << 16);
      *(uint2_ma*)(Cp + (size_t)m * 256 + n) = o;
    }
  }
}

// ------------------------------------------------------------ out-proj GEMM
__global__ __launch_bounds__(256) void gemm_out_kernel(
    const u16* __restrict__ AO, const u16* __restrict__ WOb,
    const float* __restrict__ bo, float* __restrict__ OUT) {
  alignas(16) __shared__ u16 As[2][64 * 64];
  alignas(16) __shared__ u16 Bs[2][64 * 64];
  const int tid = threadIdx.x, lane = tid & 63, wv = tid >> 6;
  const int m0 = blockIdx.x * 64, n0 = blockIdx.y * 64;

  floatx4 acc[2][2] = {};
  gemm_loop(AO + (size_t)m0 * 256, WOb + (size_t)n0 * 256, As, Bs, lane, wv, acc);

  const int wr = wv >> 1, wc = wv & 1, q4 = lane >> 4, r16 = lane & 15;
#pragma unroll
  for (int i = 0; i < 2; ++i) {
    const int m = m0 + wr * 32 + i * 16 + r16;
#pragma unroll
    for (int j = 0; j < 2; ++j) {
      const int n = n0 + wc * 32 + j * 16 + q4 * 4;
      floatx4_ma bv = *(const floatx4_ma*)(bo + n);
      floatx4_ma o;
      o[0] = acc[i][j][0] + bv[0];
      o[1] = acc[i][j][1] + bv[1];
      o[2] = acc[i][j][2] + bv[2];
      o[3] = acc[i][j][3] + bv[3];
      *(floatx4_ma*)(OUT + (size_t)m * 256 + n) = o;
    }
  }
}

// ------------------------------------------------------------ row attention
// one block per (h, s). Swapped QK^T (mfma(K,Q)) -> lane-local softmax
// (lane owns q = qbase+r16; its 64 regs + q4-peers via shfl_xor 16/32).
// Ksh padded to 40 u16/row: phase-conflict-free ds_read_b128.
// Psh is PER-WAVE -> no __syncthreads in main loop, only lgkmcnt fences.
__global__ __launch_bounds__(256) void attn_kernel(
    const u16* __restrict__ Q, const u16* __restrict__ K, const u16* __restrict__ V,
    u16* __restrict__ O) {
  alignas(16) __shared__ u16 Ksh[256 * 40];      // [kj][d], pad 32->40
  alignas(16) __shared__ u16 Vt[32 * 264];       // [d][kj], +8 pad
  alignas(16) __shared__ u16 Psh[4][16 * 256];   // per-wave P, swizzled
  const int h = blockIdx.x;
  const int s = blockIdx.y;
  const int tid = threadIdx.x;
  const int lane = tid & 63;
  const int wv = tid >> 6;
  const int q4 = lane >> 4, r16 = lane & 15;
  const size_t rowbase = (size_t)s * 256;

  {  // stage K and V^T (only cross-wave phase)
    const int r4 = tid >> 2;
    const int ch = tid & 3;
#pragma unroll
    for (int p = 0; p < 4; ++p) {
      const int row = p * 64 + r4;
      const size_t gofs = (rowbase + row) * 256 + h * 32 + ch * 8;
      *(uint4_ma*)(Ksh + row * 40 + ch * 8) = *(const uint4_ma*)(K + gofs);
      uint4_ma vvl = *(const uint4_ma*)(V + gofs);
      const u16* ve = (const u16*)&vvl;
#pragma unroll
      for (int e = 0; e < 8; ++e)
        Vt[(ch * 8 + e) * 264 + row] = ve[e];
    }
  }
  // prefetch all 4 Q fragments; latency hides under the staging barrier.
  short8 aq[4];
#pragma unroll
  for (int mt0 = 0; mt0 < 4; ++mt0)
    aq[mt0] = *(const short8*)(Q + (rowbase + (mt0 * 4 + wv) * 16 + r16) * 256 + h * 32 + q4 * 8);
  __syncthreads();

  u16* P = Psh[wv];
#pragma unroll
  for (int mt0 = 0; mt0 < 4; ++mt0) {
    const int qbase = (mt0 * 4 + wv) * 16;
    // sc[t][r] = S[k = t*16 + q4*4 + r][q = qbase + r16]
    floatx4 sc[16];
#pragma unroll
    for (int t = 0; t < 16; ++t) {
      const short8 bk = *(const short8*)(Ksh + (t * 16 + r16) * 40 + q4 * 8);
      floatx4 z = {0.f, 0.f, 0.f, 0.f};
      sc[t] = __builtin_amdgcn_mfma_f32_16x16x32_bf16(bk, aq[mt0], z, 0, 0, 0);
    }
    // lane-local softmax for q = qbase + r16
    float mx = -3.0e38f;
#pragma unroll
    for (int t = 0; t < 16; ++t)
      mx = fmaxf(mx, fmaxf(fmaxf(sc[t][0], sc[t][1]), fmaxf(sc[t][2], sc[t][3])));
    mx = fmaxf(mx, __shfl_xor(mx, 16, 64));
    mx = fmaxf(mx, __shfl_xor(mx, 32, 64));
    float sum = 0.f;
#pragma unroll
    for (int t = 0; t < 16; ++t) {
#pragma unroll
      for (int r = 0; r < 4; ++r) {
        const float p = __expf((sc[t][r] - mx) * ATT_SCALE);
        sc[t][r] = p;
        sum += p;
      }
    }
    sum += __shfl_xor(sum, 16, 64);
    sum += __shfl_xor(sum, 32, 64);
    const float inv = 1.0f / sum;
    // packed P write: row r16 (q), 4 consecutive k per t (8B each)
#pragma unroll
    for (int t = 0; t < 16; ++t) {
      const int col0 = t * 16 + q4 * 4;
      const int g = col0 >> 3, cb = col0 & 7;
      uint2_ma w;
      w.x = (u32)f2bf(sc[t][0]) | ((u32)f2bf(sc[t][1]) << 16);
      w.y = (u32)f2bf(sc[t][2]) | ((u32)f2bf(sc[t][3]) << 16);
      *(uint2_ma*)(P + r16 * 256 + ((g ^ (r16 & 7)) << 3) + cb) = w;
    }
    lds_fence();  // per-wave P: writes -> reads
    floatx4 o0 = {0.f, 0.f, 0.f, 0.f}, o1 = {0.f, 0.f, 0.f, 0.f};
#pragma unroll
    for (int kk = 0; kk < 8; ++kk) {
      const int G = kk * 4 + q4;
      const short8 ap = *(const short8*)(P + r16 * 256 + ((G ^ (r16 & 7)) << 3));
      const short8 bv0 = *(const short8*)(Vt + r16 * 264 + kk * 32 + q4 * 8);
      const short8 bv1 = *(const short8*)(Vt + (16 + r16) * 264 + kk * 32 + q4 * 8);
      o0 = __builtin_amdgcn_mfma_f32_16x16x32_bf16(bv0, ap, o0, 0, 0, 0);
      o1 = __builtin_amdgcn_mfma_f32_16x16x32_bf16(bv1, ap, o1, 0, 0, 0);
    }
    // packed O store: lane q = r16; o0 -> d = q4*4+[0..4), o1 -> +16
    const size_t ob = (rowbase + qbase + r16) * 256 + h * 32;
    uint2_ma w0, w1;
    w0.x = (u32)f2bf(o0[0] * inv) | ((u32)f2bf(o0[1] * inv) << 16);
    w0.y = (u32)f2bf(o0[2] * inv) | ((u32)f2bf(o0[3] * inv) << 16);
    w1.x = (u32)f2bf(o1[0] * inv) | ((u32)f2bf(o1[1] * inv) << 16);
    w1.y = (u32)f2bf(o1[2] * inv) | ((u32)f2bf(o1[3] * inv) << 16);
    *(uint2_ma*)(O + ob + q4 * 4) = w0;
    *(uint2_ma*)(O + ob + 16 + q4 * 4) = w1;
    lds_fence();  // P reads -> next iteration's writes
  }
}

// ---------------------------------------------------------------- launch
extern "C" void kernel_launch(void* const* d_in, const int* in_sizes, int n_in,
                              void* d_out, int out_size, void* d_ws, size_t ws_size,
                              hipStream_t stream) {
  (void)in_sizes; (void)n_in; (void)out_size;
  const float* msa = (const float*)d_in[0];
  const float* lnw = (const float*)d_in[1];
  const float* lnb = (const float*)d_in[2];
  const float* wq = (const float*)d_in[3];
  const float* wk = (const float*)d_in[4];
  const float* wvp = (const float*)d_in[5];
  const float* wo = (const float*)d_in[6];
  const float* bo = (const float*)d_in[7];
  float* out = (float*)d_out;

  // ws layout: wb (4 x 256x256 bf16 weights, 512 KiB) | per-chunk xn,q,k,v.
  u16* wb = (u16*)d_ws;
  u16* xnc = wb + 4 * 65536;
  const size_t avail = (ws_size > 524288ull) ? ws_size - 524288ull : 0;
  int CS = S;  // s-rows per chunk, pow2
  while (CS > 1 && (size_t)CS * 524288ull > avail) CS >>= 1;
  const int nch = S / CS;
  const size_t chunkElems = (size_t)CS * NRES * D;  // per tensor
  u16* qc = xnc + chunkElems;
  u16* kc = qc + chunkElems;
  u16* vc = kc + chunkElems;
  u16* aoc = xnc;  // xn dead after QKV GEMM

  wcvt_kernel<<<dim3(32, 4), 256, 0, stream>>>(wq, wk, wvp, wo, wb);

  const int mrows = CS * NRES;  // rows per chunk
  for (int c = 0; c < nch; ++c) {
    const size_t row0 = (size_t)c * mrows;
    ln_kernel<<<mrows / 4, 256, 0, stream>>>(msa + row0 * D, lnw, lnb, xnc);
    gemm_qkv_kernel<<<dim3(mrows / 64, 4, 3), 256, 0, stream>>>(xnc, wb, qc, kc, vc);
    attn_kernel<<<dim3(H, CS), 256, 0, stream>>>(qc, kc, vc, aoc);
    gemm_out_kernel<<<dim3(mrows / 64, 4), 256, 0, stream>>>(aoc, wb + 3 * 65536, bo, out + row0 * D);
  }
}

// Round 3
// 170.734 us; speedup vs baseline: 1.1339x; 1.0177x over previous
//
#include <hip/hip_runtime.h>

typedef unsigned short u16;
typedef unsigned int u32;
// may_alias: reinterpret-cast LDS/global vector access (prevent TBAA reorder).
typedef __attribute__((ext_vector_type(8), may_alias)) short short8;
typedef __attribute__((ext_vector_type(4), may_alias)) u32 uint4_ma;
typedef __attribute__((ext_vector_type(2), may_alias)) u32 uint2_ma;
typedef __attribute__((ext_vector_type(4), may_alias)) float floatx4_ma;
typedef __attribute__((ext_vector_type(4))) float floatx4;

#define DEV static __device__ __forceinline__

constexpr int S = 128, NRES = 256, D = 256, H = 8;
constexpr float ATT_SCALE = 0.17677669529663687f;  // 1/sqrt(32)

DEV u16 f2bf(float f) {
  union { float f; u32 u; } v; v.f = f;
  u32 u = v.u;
  return (u16)((u + 0x7fffu + ((u >> 16) & 1u)) >> 16);  // RNE
}

// v_cvt_pk_bf16_f32: lo16 = bf16(a), hi16 = bf16(b). 1 instr per 2 converts.
DEV u32 pkbf(float a, float b) {
  u32 r;
  asm("v_cvt_pk_bf16_f32 %0, %1, %2" : "=v"(r) : "v"(a), "v"(b));
  return r;
}

// wave-local LDS ordering: drains this wave's ds ops; full compiler memory
// barrier. Replaces __syncthreads where the LDS buffer is per-wave.
DEV void lds_fence() { asm volatile("s_waitcnt lgkmcnt(0)" ::: "memory"); }

// ---------------------------------------------------------------- LayerNorm
// f32 in, bf16 out. One wave per row of 256; float4/lane. ~BW roofline.
__global__ __launch_bounds__(256) void ln_kernel(const float* __restrict__ x,
                                                 const float* __restrict__ w,
                                                 const float* __restrict__ b,
                                                 u16* __restrict__ xn) {
  const int lane = threadIdx.x & 63;
  const int row = blockIdx.x * 4 + (threadIdx.x >> 6);
  floatx4_ma d = ((const floatx4_ma*)(x + (size_t)row * D))[lane];
  float s = d[0] + d[1] + d[2] + d[3];
  float ss = d[0] * d[0] + d[1] * d[1] + d[2] * d[2] + d[3] * d[3];
#pragma unroll
  for (int off = 32; off > 0; off >>= 1) {
    s += __shfl_xor(s, off, 64);
    ss += __shfl_xor(ss, off, 64);
  }
  const float mean = s * (1.0f / D);
  const float var = ss * (1.0f / D) - mean * mean;
  const float rstd = rsqrtf(var + 1e-5f);
  floatx4_ma wd = ((const floatx4_ma*)w)[lane];
  floatx4_ma bd = ((const floatx4_ma*)b)[lane];
  uint2_ma o;
  o.x = pkbf((d[0] - mean) * rstd * wd[0] + bd[0],
             (d[1] - mean) * rstd * wd[1] + bd[1]);
  o.y = pkbf((d[2] - mean) * rstd * wd[2] + bd[2],
             (d[3] - mean) * rstd * wd[3] + bd[3]);
  ((uint2_ma*)(xn + (size_t)row * D))[lane] = o;
}

// ------------------------------------------------- weight pre-conversion
__global__ __launch_bounds__(256) void wcvt_kernel(
    const float* __restrict__ w0, const float* __restrict__ w1,
    const float* __restrict__ w2, const float* __restrict__ w3,
    u16* __restrict__ wb) {
  const float* src = (blockIdx.y == 0) ? w0
                     : ((blockIdx.y == 1) ? w1 : ((blockIdx.y == 2) ? w2 : w3));
  u16* dst = wb + (size_t)blockIdx.y * 65536;
  const int i = (blockIdx.x * 256 + threadIdx.x) * 8;
  floatx4_ma f0 = *(const floatx4_ma*)(src + i);
  floatx4_ma f1 = *(const floatx4_ma*)(src + i + 4);
  uint4_ma hv;
  hv.x = pkbf(f0[0], f0[1]);
  hv.y = pkbf(f0[2], f0[3]);
  hv.z = pkbf(f1[0], f1[1]);
  hv.w = pkbf(f1[2], f1[3]);
  *(uint4_ma*)(dst + i) = hv;
}

// ------------------------------------------------------- GEMM staging
// 128x32 bf16 tile, pure global_load_lds DMA. LDS paired-line layout:
// elem (row,g) at line=row>>1, pos=((row&1)*4+g)^(line&7): u16 line*64+pos*8.
// Per-phase ds_read_b128 is 2-way max (free). Source is inverse-swizzled.
DEV void stage_tile(const u16* src, u16* dst, int tid) {
  const int pos = tid & 7;
  const int l0 = tid >> 3;              // line within it=0 half (0..31)
  const int pre = pos ^ (l0 & 7);
  const int row0 = l0 * 2 + (pre >> 2);
  const int g = pre & 3;
#pragma unroll
  for (int it = 0; it < 2; ++it) {
    __builtin_amdgcn_global_load_lds(
        (const __attribute__((address_space(1))) u32*)(src + (row0 + it * 64) * 256 + g * 8),
        (__attribute__((address_space(3))) u32*)(dst + (it * 256 + (tid & ~63)) * 8),
        16, 0, 0);
  }
}

// One BK=32 step: 8 ds_read_b128 + 16 MFMA per wave (2x density vs 64-tile).
// Swapped operands (mfma(b,a)): out col = A-row m, out row = W-row n ->
// each lane holds 4 consecutive n for packed stores.
DEV void mfma_step(const u16* As, const u16* Bs, int lane, int wv, floatx4 acc[4][4]) {
  const int wr = wv >> 1, wc = wv & 1;
  const int r16 = lane & 15, q4 = lane >> 4;
  const int base = (r16 >> 1) * 64 + (((r16 & 1) * 4 + q4) ^ ((r16 >> 1) & 7)) * 8;
  short8 a[4], b[4];
#pragma unroll
  for (int i = 0; i < 4; ++i) {
    a[i] = *(const short8*)(As + wr * 2048 + i * 512 + base);
    b[i] = *(const short8*)(Bs + wc * 2048 + i * 512 + base);
  }
#pragma unroll
  for (int i = 0; i < 4; ++i)
#pragma unroll
    for (int j = 0; j < 4; ++j)
      acc[i][j] = __builtin_amdgcn_mfma_f32_16x16x32_bf16(b[j], a[i], acc[i][j], 0, 0, 0);
}

// 2-phase pipelined K-loop: 8 steps of BK=32, double-buffered 32 KiB LDS.
DEV void gemm_loop128(const u16* Ab, const u16* Wb, u16 (*As)[4096], u16 (*Bs)[4096],
                      int tid, floatx4 acc[4][4]) {
  const int lane = tid & 63, wv = tid >> 6;
  stage_tile(Ab, As[0], tid);
  stage_tile(Wb, Bs[0], tid);
  __syncthreads();
#pragma unroll
  for (int ks = 0; ks < 8; ++ks) {
    const int cur = ks & 1;
    if (ks < 7) {
      stage_tile(Ab + (ks + 1) * 32, As[cur ^ 1], tid);
      stage_tile(Wb + (ks + 1) * 32, Bs[cur ^ 1], tid);
    }
    mfma_step(As[cur], Bs[cur], lane, wv, acc);
    if (ks < 7) __syncthreads();
  }
}

// ------------------------------------------------------------ QKV GEMM
__global__ __launch_bounds__(256) void gemm_qkv_kernel(
    const u16* __restrict__ A, const u16* __restrict__ wb,
    u16* __restrict__ C0, u16* __restrict__ C1, u16* __restrict__ C2) {
  alignas(16) __shared__ u16 As[2][128 * 32];
  alignas(16) __shared__ u16 Bs[2][128 * 32];
  const int tid = threadIdx.x, lane = tid & 63, wv = tid >> 6;
  const int m0 = blockIdx.x * 128, n0 = blockIdx.y * 128;
  const u16* Wp = wb + (size_t)blockIdx.z * 65536;
  u16* Cp = (blockIdx.z == 0) ? C0 : ((blockIdx.z == 1) ? C1 : C2);

  floatx4 acc[4][4] = {};
  gemm_loop128(A + (size_t)m0 * 256, Wp + (size_t)n0 * 256, As, Bs, tid, acc);

  const int wr = wv >> 1, wc = wv & 1, q4 = lane >> 4, r16 = lane & 15;
#pragma unroll
  for (int i = 0; i < 4; ++i) {
    const int m = m0 + wr * 64 + i * 16 + r16;
#pragma unroll
    for (int j = 0; j < 4; ++j) {
      const int n = n0 + wc * 64 + j * 16 + q4 * 4;
      uint2_ma o;
      o.x = pkbf(acc[i][j][0], acc[i][j][1]);
      o.y = pkbf(acc[i][j][2], acc[i][j][3]);
      *(uint2_ma*)(Cp + (size_t)m * 256 + n) = o;
    }
  }
}

// ------------------------------------------------------------ out-proj GEMM
__global__ __launch_bounds__(256) void gemm_out_kernel(
    const u16* __restrict__ AO, const u16* __restrict__ WOb,
    const float* __restrict__ bo, float* __restrict__ OUT) {
  alignas(16) __shared__ u16 As[2][128 * 32];
  alignas(16) __shared__ u16 Bs[2][128 * 32];
  const int tid = threadIdx.x, lane = tid & 63, wv = tid >> 6;
  const int m0 = blockIdx.x * 128, n0 = blockIdx.y * 128;

  floatx4 acc[4][4] = {};
  gemm_loop128(AO + (size_t)m0 * 256, WOb + (size_t)n0 * 256, As, Bs, tid, acc);

  const int wr = wv >> 1, wc = wv & 1, q4 = lane >> 4, r16 = lane & 15;
#pragma unroll
  for (int i = 0; i < 4; ++i) {
    const int m = m0 + wr * 64 + i * 16 + r16;
#pragma unroll
    for (int j = 0; j < 4; ++j) {
      const int n = n0 + wc * 64 + j * 16 + q4 * 4;
      floatx4_ma bv = *(const floatx4_ma*)(bo + n);
      floatx4_ma o;
      o[0] = acc[i][j][0] + bv[0];
      o[1] = acc[i][j][1] + bv[1];
      o[2] = acc[i][j][2] + bv[2];
      o[3] = acc[i][j][3] + bv[3];
      *(floatx4_ma*)(OUT + (size_t)m * 256 + n) = o;
    }
  }
}

// ------------------------------------------------------------ row attention
// ROUND-1-VERIFIED VERSION (verbatim). one block per (h, s). Swapped QK^T
// (mfma(K,Q)) -> lane-local softmax. Ksh padded to 40 u16/row. Psh per-wave,
// wave-local lgkmcnt fences instead of __syncthreads in the main loop.
__global__ __launch_bounds__(256) void attn_kernel(
    const u16* __restrict__ Q, const u16* __restrict__ K, const u16* __restrict__ V,
    u16* __restrict__ O) {
  alignas(16) __shared__ u16 Ksh[256 * 40];      // [kj][d], pad 32->40
  alignas(16) __shared__ u16 Vt[32 * 264];       // [d][kj], +8 pad
  alignas(16) __shared__ u16 Psh[4][16 * 256];   // per-wave P, swizzled
  const int h = blockIdx.x;
  const int s = blockIdx.y;
  const int tid = threadIdx.x;
  const int lane = tid & 63;
  const int wv = tid >> 6;
  const int q4 = lane >> 4, r16 = lane & 15;
  const size_t rowbase = (size_t)s * 256;

  {  // stage K and V^T (only cross-wave phase)
    const int r4 = tid >> 2;
    const int ch = tid & 3;
#pragma unroll
    for (int p = 0; p < 4; ++p) {
      const int row = p * 64 + r4;
      const size_t gofs = (rowbase + row) * 256 + h * 32 + ch * 8;
      *(uint4_ma*)(Ksh + row * 40 + ch * 8) = *(const uint4_ma*)(K + gofs);
      uint4_ma vvl = *(const uint4_ma*)(V + gofs);
      const u16* ve = (const u16*)&vvl;
#pragma unroll
      for (int e = 0; e < 8; ++e)
        Vt[(ch * 8 + e) * 264 + row] = ve[e];
    }
  }
  // prefetch all 4 Q fragments; latency hides under the staging barrier.
  short8 aq[4];
#pragma unroll
  for (int mt0 = 0; mt0 < 4; ++mt0)
    aq[mt0] = *(const short8*)(Q + (rowbase + (mt0 * 4 + wv) * 16 + r16) * 256 + h * 32 + q4 * 8);
  __syncthreads();

  u16* P = Psh[wv];
#pragma unroll
  for (int mt0 = 0; mt0 < 4; ++mt0) {
    const int qbase = (mt0 * 4 + wv) * 16;
    // sc[t][r] = S[k = t*16 + q4*4 + r][q = qbase + r16]
    floatx4 sc[16];
#pragma unroll
    for (int t = 0; t < 16; ++t) {
      const short8 bk = *(const short8*)(Ksh + (t * 16 + r16) * 40 + q4 * 8);
      floatx4 z = {0.f, 0.f, 0.f, 0.f};
      sc[t] = __builtin_amdgcn_mfma_f32_16x16x32_bf16(bk, aq[mt0], z, 0, 0, 0);
    }
    // lane-local softmax for q = qbase + r16 (combine q4-peers via xor16/32)
    float mx = -3.0e38f;
#pragma unroll
    for (int t = 0; t < 16; ++t)
      mx = fmaxf(mx, fmaxf(fmaxf(sc[t][0], sc[t][1]), fmaxf(sc[t][2], sc[t][3])));
    mx = fmaxf(mx, __shfl_xor(mx, 16, 64));
    mx = fmaxf(mx, __shfl_xor(mx, 32, 64));
    float sum = 0.f;
#pragma unroll
    for (int t = 0; t < 16; ++t) {
#pragma unroll
      for (int r = 0; r < 4; ++r) {
        const float p = __expf((sc[t][r] - mx) * ATT_SCALE);
        sc[t][r] = p;
        sum += p;
      }
    }
    sum += __shfl_xor(sum, 16, 64);
    sum += __shfl_xor(sum, 32, 64);
    const float inv = 1.0f / sum;
    // packed P write: row r16 (q), 4 consecutive k per t (8B each)
#pragma unroll
    for (int t = 0; t < 16; ++t) {
      const int col0 = t * 16 + q4 * 4;
      const int g = col0 >> 3, cb = col0 & 7;
      uint2_ma w;
      w.x = (u32)f2bf(sc[t][0]) | ((u32)f2bf(sc[t][1]) << 16);
      w.y = (u32)f2bf(sc[t][2]) | ((u32)f2bf(sc[t][3]) << 16);
      *(uint2_ma*)(P + r16 * 256 + ((g ^ (r16 & 7)) << 3) + cb) = w;
    }
    lds_fence();  // per-wave P: writes -> reads
    floatx4 o0 = {0.f, 0.f, 0.f, 0.f}, o1 = {0.f, 0.f, 0.f, 0.f};
#pragma unroll
    for (int kk = 0; kk < 8; ++kk) {
      const int G = kk * 4 + q4;
      const short8 ap = *(const short8*)(P + r16 * 256 + ((G ^ (r16 & 7)) << 3));
      const short8 bv0 = *(const short8*)(Vt + r16 * 264 + kk * 32 + q4 * 8);
      const short8 bv1 = *(const short8*)(Vt + (16 + r16) * 264 + kk * 32 + q4 * 8);
      o0 = __builtin_amdgcn_mfma_f32_16x16x32_bf16(bv0, ap, o0, 0, 0, 0);
      o1 = __builtin_amdgcn_mfma_f32_16x16x32_bf16(bv1, ap, o1, 0, 0, 0);
    }
    // o0[r] = out[d = q4*4+r][q = r16]; o1 -> d+16. Packed 8B stores.
    const size_t ob = (rowbase + qbase + r16) * 256 + h * 32;
    uint2_ma w0, w1;
    w0.x = (u32)f2bf(o0[0] * inv) | ((u32)f2bf(o0[1] * inv) << 16);
    w0.y = (u32)f2bf(o0[2] * inv) | ((u32)f2bf(o0[3] * inv) << 16);
    w1.x = (u32)f2bf(o1[0] * inv) | ((u32)f2bf(o1[1] * inv) << 16);
    w1.y = (u32)f2bf(o1[2] * inv) | ((u32)f2bf(o1[3] * inv) << 16);
    *(uint2_ma*)(O + ob + q4 * 4) = w0;
    *(uint2_ma*)(O + ob + 16 + q4 * 4) = w1;
    lds_fence();  // P reads -> next iter's writes
  }
}

// ---------------------------------------------------------------- launch
extern "C" void kernel_launch(void* const* d_in, const int* in_sizes, int n_in,
                              void* d_out, int out_size, void* d_ws, size_t ws_size,
                              hipStream_t stream) {
  (void)in_sizes; (void)n_in; (void)out_size;
  const float* msa = (const float*)d_in[0];
  const float* lnw = (const float*)d_in[1];
  const float* lnb = (const float*)d_in[2];
  const float* wq = (const float*)d_in[3];
  const float* wk = (const float*)d_in[4];
  const float* wvp = (const float*)d_in[5];
  const float* wo = (const float*)d_in[6];
  const float* bo = (const float*)d_in[7];
  float* out = (float*)d_out;

  // ws layout: wb (4 x 256x256 bf16 weights, 512 KiB) | per-chunk xn,q,k,v.
  u16* wb = (u16*)d_ws;
  u16* xnc = wb + 4 * 65536;
  const size_t avail = (ws_size > 524288ull) ? ws_size - 524288ull : 0;
  int CS = S;  // s-rows per chunk, pow2
  while (CS > 1 && (size_t)CS * 524288ull > avail) CS >>= 1;
  const int nch = S / CS;
  const size_t chunkElems = (size_t)CS * NRES * D;  // per tensor
  u16* qc = xnc + chunkElems;
  u16* kc = qc + chunkElems;
  u16* vc = kc + chunkElems;
  u16* aoc = xnc;  // xn dead after QKV GEMM

  wcvt_kernel<<<dim3(32, 4), 256, 0, stream>>>(wq, wk, wvp, wo, wb);

  const int mrows = CS * NRES;  // rows per chunk
  for (int c = 0; c < nch; ++c) {
    const size_t row0 = (size_t)c * mrows;
    ln_kernel<<<mrows / 4, 256, 0, stream>>>(msa + row0 * D, lnw, lnb, xnc);
    gemm_qkv_kernel<<<dim3(mrows / 128, 2, 3), 256, 0, stream>>>(xnc, wb, qc, kc, vc);
    attn_kernel<<<dim3(H, CS), 256, 0, stream>>>(qc, kc, vc, aoc);
    gemm_out_kernel<<<dim3(mrows / 128, 2), 256, 0, stream>>>(aoc, wb + 3 * 65536, bo, out + row0 * D);
  }
}

// Round 4
// 170.245 us; speedup vs baseline: 1.1371x; 1.0029x over previous
//
#include <hip/hip_runtime.h>

typedef unsigned short u16;
typedef unsigned int u32;
// may_alias: reinterpret-cast LDS/global vector access (prevent TBAA reorder).
typedef __attribute__((ext_vector_type(8), may_alias)) short short8;
typedef __attribute__((ext_vector_type(4), may_alias)) u32 uint4_ma;
typedef __attribute__((ext_vector_type(2), may_alias)) u32 uint2_ma;
typedef __attribute__((ext_vector_type(4), may_alias)) float floatx4_ma;
typedef __attribute__((ext_vector_type(4))) float floatx4;

#define DEV static __device__ __forceinline__

constexpr int S = 128, NRES = 256, D = 256, H = 8;
constexpr float ATT_SCALE = 0.17677669529663687f;  // 1/sqrt(32)

// v_cvt_pk_bf16_f32: lo16 = bf16(a), hi16 = bf16(b). VERIFIED round 3
// (gemm_out: honest A vs pkbf W passed -> order cannot be swapped).
DEV u32 pkbf(float a, float b) {
  u32 r;
  asm("v_cvt_pk_bf16_f32 %0, %1, %2" : "=v"(r) : "v"(a), "v"(b));
  return r;
}

union P8 { u32 w[4]; short8 v; };

// ---------------------------------------------------------------- LayerNorm
// f32 in, bf16 out. One wave per row of 256; float4/lane. ~BW roofline.
__global__ __launch_bounds__(256) void ln_kernel(const float* __restrict__ x,
                                                 const float* __restrict__ w,
                                                 const float* __restrict__ b,
                                                 u16* __restrict__ xn) {
  const int lane = threadIdx.x & 63;
  const int row = blockIdx.x * 4 + (threadIdx.x >> 6);
  floatx4_ma d = ((const floatx4_ma*)(x + (size_t)row * D))[lane];
  float s = d[0] + d[1] + d[2] + d[3];
  float ss = d[0] * d[0] + d[1] * d[1] + d[2] * d[2] + d[3] * d[3];
#pragma unroll
  for (int off = 32; off > 0; off >>= 1) {
    s += __shfl_xor(s, off, 64);
    ss += __shfl_xor(ss, off, 64);
  }
  const float mean = s * (1.0f / D);
  const float var = ss * (1.0f / D) - mean * mean;
  const float rstd = rsqrtf(var + 1e-5f);
  floatx4_ma wd = ((const floatx4_ma*)w)[lane];
  floatx4_ma bd = ((const floatx4_ma*)b)[lane];
  uint2_ma o;
  o.x = pkbf((d[0] - mean) * rstd * wd[0] + bd[0],
             (d[1] - mean) * rstd * wd[1] + bd[1]);
  o.y = pkbf((d[2] - mean) * rstd * wd[2] + bd[2],
             (d[3] - mean) * rstd * wd[3] + bd[3]);
  ((uint2_ma*)(xn + (size_t)row * D))[lane] = o;
}

// ------------------------------------------------- weight pre-conversion
__global__ __launch_bounds__(256) void wcvt_kernel(
    const float* __restrict__ w0, const float* __restrict__ w1,
    const float* __restrict__ w2, const float* __restrict__ w3,
    u16* __restrict__ wb) {
  const float* src = (blockIdx.y == 0) ? w0
                     : ((blockIdx.y == 1) ? w1 : ((blockIdx.y == 2) ? w2 : w3));
  u16* dst = wb + (size_t)blockIdx.y * 65536;
  const int i = (blockIdx.x * 256 + threadIdx.x) * 8;
  floatx4_ma f0 = *(const floatx4_ma*)(src + i);
  floatx4_ma f1 = *(const floatx4_ma*)(src + i + 4);
  uint4_ma hv;
  hv.x = pkbf(f0[0], f0[1]);
  hv.y = pkbf(f0[2], f0[3]);
  hv.z = pkbf(f1[0], f1[1]);
  hv.w = pkbf(f1[2], f1[3]);
  *(uint4_ma*)(dst + i) = hv;
}

// ------------------------------------------------------- GEMM staging
// 128x32 bf16 tile, pure global_load_lds DMA. LDS paired-line layout:
// elem (row,g) at line=row>>1, pos=((row&1)*4+g)^(line&7): u16 line*64+pos*8.
// Per-phase ds_read_b128 is 2-way max (free). Source is inverse-swizzled.
// VERIFIED (round 3 pass).
DEV void stage_tile(const u16* src, u16* dst, int tid) {
  const int pos = tid & 7;
  const int l0 = tid >> 3;              // line within it=0 half (0..31)
  const int pre = pos ^ (l0 & 7);
  const int row0 = l0 * 2 + (pre >> 2);
  const int g = pre & 3;
#pragma unroll
  for (int it = 0; it < 2; ++it) {
    __builtin_amdgcn_global_load_lds(
        (const __attribute__((address_space(1))) u32*)(src + (row0 + it * 64) * 256 + g * 8),
        (__attribute__((address_space(3))) u32*)(dst + (it * 256 + (tid & ~63)) * 8),
        16, 0, 0);
  }
}

// One BK=32 step: 8 ds_read_b128 + 16 MFMA per wave.
// SWAP=false: acc = mfma(b,a) -> lane holds 4 consecutive n (packed C store).
// SWAP=true:  acc = mfma(a,b) -> lane holds 4 consecutive m (packed V^T store).
template <bool SWAP>
DEV void mfma_step(const u16* As, const u16* Bs, int lane, int wv, floatx4 acc[4][4]) {
  const int wr = wv >> 1, wc = wv & 1;
  const int r16 = lane & 15, q4 = lane >> 4;
  const int base = (r16 >> 1) * 64 + (((r16 & 1) * 4 + q4) ^ ((r16 >> 1) & 7)) * 8;
  short8 a[4], b[4];
#pragma unroll
  for (int i = 0; i < 4; ++i) {
    a[i] = *(const short8*)(As + wr * 2048 + i * 512 + base);
    b[i] = *(const short8*)(Bs + wc * 2048 + i * 512 + base);
  }
#pragma unroll
  for (int i = 0; i < 4; ++i)
#pragma unroll
    for (int j = 0; j < 4; ++j)
      acc[i][j] = SWAP
          ? __builtin_amdgcn_mfma_f32_16x16x32_bf16(a[i], b[j], acc[i][j], 0, 0, 0)
          : __builtin_amdgcn_mfma_f32_16x16x32_bf16(b[j], a[i], acc[i][j], 0, 0, 0);
}

// 2-phase pipelined K-loop: 8 steps of BK=32, double-buffered 32 KiB LDS.
template <bool SWAP>
DEV void gemm_loop128(const u16* Ab, const u16* Wb, u16 (*As)[4096], u16 (*Bs)[4096],
                      int tid, floatx4 acc[4][4]) {
  const int lane = tid & 63, wv = tid >> 6;
  stage_tile(Ab, As[0], tid);
  stage_tile(Wb, Bs[0], tid);
  __syncthreads();
#pragma unroll
  for (int ks = 0; ks < 8; ++ks) {
    const int cur = ks & 1;
    if (ks < 7) {
      stage_tile(Ab + (ks + 1) * 32, As[cur ^ 1], tid);
      stage_tile(Wb + (ks + 1) * 32, Bs[cur ^ 1], tid);
    }
    mfma_step<SWAP>(As[cur], Bs[cur], lane, wv, acc);
    if (ks < 7) __syncthreads();
  }
}

// ------------------------------------------------------------ Q/K GEMM
__global__ __launch_bounds__(256) void gemm_qkv_kernel(
    const u16* __restrict__ A, const u16* __restrict__ wb,
    u16* __restrict__ C0, u16* __restrict__ C1) {
  alignas(16) __shared__ u16 As[2][128 * 32];
  alignas(16) __shared__ u16 Bs[2][128 * 32];
  const int tid = threadIdx.x, lane = tid & 63, wv = tid >> 6;
  const int m0 = blockIdx.x * 128, n0 = blockIdx.y * 128;
  const u16* Wp = wb + (size_t)blockIdx.z * 65536;
  u16* Cp = (blockIdx.z == 0) ? C0 : C1;

  floatx4 acc[4][4] = {};
  gemm_loop128<false>(A + (size_t)m0 * 256, Wp + (size_t)n0 * 256, As, Bs, tid, acc);

  const int wr = wv >> 1, wc = wv & 1, q4 = lane >> 4, r16 = lane & 15;
#pragma unroll
  for (int i = 0; i < 4; ++i) {
    const int m = m0 + wr * 64 + i * 16 + r16;
#pragma unroll
    for (int j = 0; j < 4; ++j) {
      const int n = n0 + wc * 64 + j * 16 + q4 * 4;
      uint2_ma o;
      o.x = pkbf(acc[i][j][0], acc[i][j][1]);
      o.y = pkbf(acc[i][j][2], acc[i][j][3]);
      *(uint2_ma*)(Cp + (size_t)m * 256 + n) = o;
    }
  }
}

// ------------------------------------------------------------ V^T GEMM
// Same verified loop, SWAP'd operands: lane reg r = C[m=mb+q4*4+r][n=d].
// Stores V^T[d][pcol(m)] where pcol bakes in the PV k-window permutation:
// within each 32-block, p = q4*8 + half*4 + e  <->  k = half*16 + q4*4 + e.
// Still one packed 8B store per quad (r=0..3 -> consecutive p).
__global__ __launch_bounds__(256) void gemm_vT_kernel(
    const u16* __restrict__ A, const u16* __restrict__ Wv,
    u16* __restrict__ VT, int mstride) {
  alignas(16) __shared__ u16 As[2][128 * 32];
  alignas(16) __shared__ u16 Bs[2][128 * 32];
  const int tid = threadIdx.x, lane = tid & 63, wv = tid >> 6;
  const int m0 = blockIdx.x * 128, n0 = blockIdx.y * 128;

  floatx4 acc[4][4] = {};
  gemm_loop128<true>(A + (size_t)m0 * 256, Wv + (size_t)n0 * 256, As, Bs, tid, acc);

  const int wr = wv >> 1, wc = wv & 1, q4 = lane >> 4, r16 = lane & 15;
#pragma unroll
  for (int i = 0; i < 4; ++i) {
    const int mb = m0 + wr * 64 + i * 16;  // 16-aligned
    const int pc = (mb & ~31) + q4 * 8 + ((mb >> 4) & 1) * 4;
#pragma unroll
    for (int j = 0; j < 4; ++j) {
      const int d = n0 + wc * 64 + j * 16 + r16;
      uint2_ma o;
      o.x = pkbf(acc[i][j][0], acc[i][j][1]);
      o.y = pkbf(acc[i][j][2], acc[i][j][3]);
      *(uint2_ma*)(VT + (size_t)d * mstride + pc) = o;
    }
  }
}

// ------------------------------------------------------------ out-proj GEMM
__global__ __launch_bounds__(256) void gemm_out_kernel(
    const u16* __restrict__ AO, const u16* __restrict__ WOb,
    const float* __restrict__ bo, float* __restrict__ OUT) {
  alignas(16) __shared__ u16 As[2][128 * 32];
  alignas(16) __shared__ u16 Bs[2][128 * 32];
  const int tid = threadIdx.x, lane = tid & 63, wv = tid >> 6;
  const int m0 = blockIdx.x * 128, n0 = blockIdx.y * 128;

  floatx4 acc[4][4] = {};
  gemm_loop128<false>(AO + (size_t)m0 * 256, WOb + (size_t)n0 * 256, As, Bs, tid, acc);

  const int wr = wv >> 1, wc = wv & 1, q4 = lane >> 4, r16 = lane & 15;
#pragma unroll
  for (int i = 0; i < 4; ++i) {
    const int m = m0 + wr * 64 + i * 16 + r16;
#pragma unroll
    for (int j = 0; j < 4; ++j) {
      const int n = n0 + wc * 64 + j * 16 + q4 * 4;
      floatx4_ma bv = *(const floatx4_ma*)(bo + n);
      floatx4_ma o;
      o[0] = acc[i][j][0] + bv[0];
      o[1] = acc[i][j][1] + bv[1];
      o[2] = acc[i][j][2] + bv[2];
      o[3] = acc[i][j][3] + bv[3];
      *(floatx4_ma*)(OUT + (size_t)m * 256 + n) = o;
    }
  }
}

// ------------------------------------------------------------ row attention
// One block per (h, s). K staged by two verified stage_tile DMAs; V^T staged
// by DMA from the pre-transposed+permuted VT with a granule-XOR swizzle.
// Swapped QK^T (mfma(K,Q)) -> lane-local softmax. PV's P operand is the
// lane's OWN sc registers via the permuted K=32 window (slot (q4,e) carries
// k = 32kk + 16*(e>=4) + q4*4 + (e&3) on BOTH operands -> pure relabeling,
// mathematically exact). No P LDS, no fences, no barriers after staging.
__global__ __launch_bounds__(256) void attn_kernel(
    const u16* __restrict__ Q, const u16* __restrict__ K,
    const u16* __restrict__ VT, u16* __restrict__ O, int mstride) {
  alignas(16) __shared__ u16 Ksh[2][4096];   // 16 KiB, paired-line swizzle
  alignas(16) __shared__ u16 Vlds[32 * 256]; // 16 KiB, granule-XOR swizzle
  const int h = blockIdx.x;
  const int s = blockIdx.y;
  const int tid = threadIdx.x;
  const int lane = tid & 63;
  const int wv = tid >> 6;
  const int q4 = lane >> 4, r16 = lane & 15;
  const size_t rowbase = (size_t)s * 256;

  // stage K rows 0..255 (head slice) via the GEMM-verified path
  stage_tile(K + rowbase * 256 + h * 32, Ksh[0], tid);
  stage_tile(K + (rowbase + 128) * 256 + h * 32, Ksh[1], tid);
  {  // stage V^T: slot (d, g') <- source granule g = (g'&24)|((g'^d)&7)
    const u16* vsrc = VT + (size_t)(h * 32) * mstride + rowbase;
#pragma unroll
    for (int it = 0; it < 4; ++it) {
      const int slot = it * 256 + tid;
      const int d = slot >> 5, gp = slot & 31;
      const int g = (gp & 24) | ((gp ^ d) & 7);
      __builtin_amdgcn_global_load_lds(
          (const __attribute__((address_space(1))) u32*)(vsrc + (size_t)d * mstride + g * 8),
          (__attribute__((address_space(3))) u32*)(Vlds + (it * 256 + (tid & ~63)) * 8),
          16, 0, 0);
    }
  }
  // Q prefetch (latency hides under the staging barrier)
  short8 aq[4];
#pragma unroll
  for (int mt0 = 0; mt0 < 4; ++mt0)
    aq[mt0] = *(const short8*)(Q + (rowbase + (mt0 * 4 + wv) * 16 + r16) * 256 + h * 32 + q4 * 8);
  __syncthreads();  // drains vmcnt (DMA) before any wave proceeds

  // lane-constant K fragment base (row = t*16 + r16, granule = q4)
  const int kbase = (r16 >> 1) * 64 + ((((r16 & 1) * 4 + q4) ^ ((r16 >> 1) & 7)) << 3);

#pragma unroll
  for (int mt0 = 0; mt0 < 4; ++mt0) {
    const int qbase = (mt0 * 4 + wv) * 16;
    // sc[t][r] = S[k = t*16 + q4*4 + r][q = qbase + r16]
    floatx4 sc[16];
#pragma unroll
    for (int t = 0; t < 16; ++t) {
      const short8 bk = *(const short8*)(&Ksh[t >> 3][(t & 7) * 512 + kbase]);
      floatx4 z = {0.f, 0.f, 0.f, 0.f};
      sc[t] = __builtin_amdgcn_mfma_f32_16x16x32_bf16(bk, aq[mt0], z, 0, 0, 0);
    }
    // lane-local softmax for q = qbase + r16 (combine q4-peers via xor16/32)
    float mx = -3.0e38f;
#pragma unroll
    for (int t = 0; t < 16; ++t)
      mx = fmaxf(mx, fmaxf(fmaxf(sc[t][0], sc[t][1]), fmaxf(sc[t][2], sc[t][3])));
    mx = fmaxf(mx, __shfl_xor(mx, 16, 64));
    mx = fmaxf(mx, __shfl_xor(mx, 32, 64));
    float sum = 0.f;
#pragma unroll
    for (int t = 0; t < 16; ++t) {
#pragma unroll
      for (int r = 0; r < 4; ++r) {
        const float p = __expf((sc[t][r] - mx) * ATT_SCALE);
        sc[t][r] = p;
        sum += p;
      }
    }
    sum += __shfl_xor(sum, 16, 64);
    sum += __shfl_xor(sum, 32, 64);
    const float inv = 1.0f / sum;

    // PV: P operand = own registers (permuted window), V = 2x ds_read_b128.
    floatx4 o0 = {0.f, 0.f, 0.f, 0.f}, o1 = {0.f, 0.f, 0.f, 0.f};
#pragma unroll
    for (int kk = 0; kk < 8; ++kk) {
      const int gv = kk * 4 + q4;
      const int goff = ((gv & 24) | ((gv ^ (r16 & 7)) & 7)) << 3;
      const short8 bv0 = *(const short8*)(Vlds + r16 * 256 + goff);
      const short8 bv1 = *(const short8*)(Vlds + (16 + r16) * 256 + goff);
      P8 ap;  // slots: e<4 -> sc[2kk][e] (k=32kk+q4*4+e); e>=4 -> sc[2kk+1]
      ap.w[0] = pkbf(sc[2 * kk][0], sc[2 * kk][1]);
      ap.w[1] = pkbf(sc[2 * kk][2], sc[2 * kk][3]);
      ap.w[2] = pkbf(sc[2 * kk + 1][0], sc[2 * kk + 1][1]);
      ap.w[3] = pkbf(sc[2 * kk + 1][2], sc[2 * kk + 1][3]);
      o0 = __builtin_amdgcn_mfma_f32_16x16x32_bf16(bv0, ap.v, o0, 0, 0, 0);
      o1 = __builtin_amdgcn_mfma_f32_16x16x32_bf16(bv1, ap.v, o1, 0, 0, 0);
    }
    // o0[r] = out[d = q4*4+r][q = r16]; o1 -> d+16. Packed 8B stores.
    const size_t ob = (rowbase + qbase + r16) * 256 + h * 32;
    uint2_ma w0, w1;
    w0.x = pkbf(o0[0] * inv, o0[1] * inv);
    w0.y = pkbf(o0[2] * inv, o0[3] * inv);
    w1.x = pkbf(o1[0] * inv, o1[1] * inv);
    w1.y = pkbf(o1[2] * inv, o1[3] * inv);
    *(uint2_ma*)(O + ob + q4 * 4) = w0;
    *(uint2_ma*)(O + ob + 16 + q4 * 4) = w1;
  }
}

// ---------------------------------------------------------------- launch
extern "C" void kernel_launch(void* const* d_in, const int* in_sizes, int n_in,
                              void* d_out, int out_size, void* d_ws, size_t ws_size,
                              hipStream_t stream) {
  (void)in_sizes; (void)n_in; (void)out_size;
  const float* msa = (const float*)d_in[0];
  const float* lnw = (const float*)d_in[1];
  const float* lnb = (const float*)d_in[2];
  const float* wq = (const float*)d_in[3];
  const float* wk = (const float*)d_in[4];
  const float* wvp = (const float*)d_in[5];
  const float* wo = (const float*)d_in[6];
  const float* bo = (const float*)d_in[7];
  float* out = (float*)d_out;

  // ws layout: wb (4 x 256x256 bf16 weights, 512 KiB) | per-chunk xn,q,k,vT.
  u16* wb = (u16*)d_ws;
  u16* xnc = wb + 4 * 65536;
  const size_t avail = (ws_size > 524288ull) ? ws_size - 524288ull : 0;
  int CS = S;  // s-rows per chunk, pow2
  while (CS > 1 && (size_t)CS * 524288ull > avail) CS >>= 1;
  const int nch = S / CS;
  const size_t chunkElems = (size_t)CS * NRES * D;  // per tensor
  u16* qc = xnc + chunkElems;
  u16* kc = qc + chunkElems;
  u16* vtc = kc + chunkElems;  // V^T [256 d][mrows], permuted cols
  u16* aoc = xnc;              // xn dead after QKV GEMM

  wcvt_kernel<<<dim3(32, 4), 256, 0, stream>>>(wq, wk, wvp, wo, wb);

  const int mrows = CS * NRES;  // rows per chunk
  for (int c = 0; c < nch; ++c) {
    const size_t row0 = (size_t)c * mrows;
    ln_kernel<<<mrows / 4, 256, 0, stream>>>(msa + row0 * D, lnw, lnb, xnc);
    gemm_qkv_kernel<<<dim3(mrows / 128, 2, 2), 256, 0, stream>>>(xnc, wb, qc, kc);
    gemm_vT_kernel<<<dim3(mrows / 128, 2), 256, 0, stream>>>(xnc, wb + 2 * 65536, vtc, mrows);
    attn_kernel<<<dim3(H, CS), 256, 0, stream>>>(qc, kc, vtc, aoc, mrows);
    gemm_out_kernel<<<dim3(mrows / 128, 2), 256, 0, stream>>>(aoc, wb + 3 * 65536, bo, out + row0 * D);
  }
}

// Round 5
// 162.247 us; speedup vs baseline: 1.1932x; 1.0493x over previous
//
#include <hip/hip_runtime.h>

typedef unsigned short u16;
typedef unsigned int u32;
// may_alias: reinterpret-cast LDS/global vector access (prevent TBAA reorder).
typedef __attribute__((ext_vector_type(8), may_alias)) short short8;
typedef __attribute__((ext_vector_type(4), may_alias)) u32 uint4_ma;
typedef __attribute__((ext_vector_type(2), may_alias)) u32 uint2_ma;
typedef __attribute__((ext_vector_type(4), may_alias)) float floatx4_ma;
typedef __attribute__((ext_vector_type(4))) float floatx4;

#define DEV static __device__ __forceinline__

constexpr int S = 128, NRES = 256, D = 256, H = 8;
// Q is pre-scaled by ATT_SCALE*log2(e) in the QKV epilogue, so softmax is
// p = exp2(sc - mx) exactly: e^{ATT_SCALE*(score-max)}.
constexpr float QSC = 0.25503486f;  // (1/sqrt(32)) * log2(e)

// v_cvt_pk_bf16_f32: lo16 = bf16(a), hi16 = bf16(b). VERIFIED round 3
// (gemm_out: honest A vs pkbf W passed -> order cannot be swapped).
DEV u32 pkbf(float a, float b) {
  u32 r;
  asm("v_cvt_pk_bf16_f32 %0, %1, %2" : "=v"(r) : "v"(a), "v"(b));
  return r;
}

#if __has_builtin(__builtin_amdgcn_exp2f)
DEV float exp2g(float x) { return __builtin_amdgcn_exp2f(x); }
#else
DEV float exp2g(float x) { return __expf(x * 0.6931471805599453f); }
#endif

union P8 { u32 w[4]; short8 v; };

// ---------------------------------------------------------------- LayerNorm
// f32 in, bf16 out. One wave per row of 256; float4/lane. ~BW roofline.
__global__ __launch_bounds__(256) void ln_kernel(const float* __restrict__ x,
                                                 const float* __restrict__ w,
                                                 const float* __restrict__ b,
                                                 u16* __restrict__ xn) {
  const int lane = threadIdx.x & 63;
  const int row = blockIdx.x * 4 + (threadIdx.x >> 6);
  floatx4_ma d = ((const floatx4_ma*)(x + (size_t)row * D))[lane];
  float s = d[0] + d[1] + d[2] + d[3];
  float ss = d[0] * d[0] + d[1] * d[1] + d[2] * d[2] + d[3] * d[3];
#pragma unroll
  for (int off = 32; off > 0; off >>= 1) {
    s += __shfl_xor(s, off, 64);
    ss += __shfl_xor(ss, off, 64);
  }
  const float mean = s * (1.0f / D);
  const float var = ss * (1.0f / D) - mean * mean;
  const float rstd = rsqrtf(var + 1e-5f);
  floatx4_ma wd = ((const floatx4_ma*)w)[lane];
  floatx4_ma bd = ((const floatx4_ma*)b)[lane];
  uint2_ma o;
  o.x = pkbf((d[0] - mean) * rstd * wd[0] + bd[0],
             (d[1] - mean) * rstd * wd[1] + bd[1]);
  o.y = pkbf((d[2] - mean) * rstd * wd[2] + bd[2],
             (d[3] - mean) * rstd * wd[3] + bd[3]);
  ((uint2_ma*)(xn + (size_t)row * D))[lane] = o;
}

// ------------------------------------------------- weight pre-conversion
__global__ __launch_bounds__(256) void wcvt_kernel(
    const float* __restrict__ w0, const float* __restrict__ w1,
    const float* __restrict__ w2, const float* __restrict__ w3,
    u16* __restrict__ wb) {
  const float* src = (blockIdx.y == 0) ? w0
                     : ((blockIdx.y == 1) ? w1 : ((blockIdx.y == 2) ? w2 : w3));
  u16* dst = wb + (size_t)blockIdx.y * 65536;
  const int i = (blockIdx.x * 256 + threadIdx.x) * 8;
  floatx4_ma f0 = *(const floatx4_ma*)(src + i);
  floatx4_ma f1 = *(const floatx4_ma*)(src + i + 4);
  uint4_ma hv;
  hv.x = pkbf(f0[0], f0[1]);
  hv.y = pkbf(f0[2], f0[3]);
  hv.z = pkbf(f1[0], f1[1]);
  hv.w = pkbf(f1[2], f1[3]);
  *(uint4_ma*)(dst + i) = hv;
}

// ------------------------------------------------------- GEMM staging
// 128x32 bf16 tile, pure global_load_lds DMA. LDS paired-line layout:
// elem (row,g) at line=row>>1, pos=((row&1)*4+g)^(line&7): u16 line*64+pos*8.
// Per-phase ds_read_b128 is 2-way max (free). Source is inverse-swizzled.
// VERIFIED (rounds 3/4 pass).
DEV void stage_tile(const u16* src, u16* dst, int tid) {
  const int pos = tid & 7;
  const int l0 = tid >> 3;              // line within it=0 half (0..31)
  const int pre = pos ^ (l0 & 7);
  const int row0 = l0 * 2 + (pre >> 2);
  const int g = pre & 3;
#pragma unroll
  for (int it = 0; it < 2; ++it) {
    __builtin_amdgcn_global_load_lds(
        (const __attribute__((address_space(1))) u32*)(src + (row0 + it * 64) * 256 + g * 8),
        (__attribute__((address_space(3))) u32*)(dst + (it * 256 + (tid & ~63)) * 8),
        16, 0, 0);
  }
}

// One BK=32 step: 8 ds_read_b128 + 16 MFMA per wave. VERIFIED (rounds 3/4).
// SWAP=false: acc = mfma(b,a) -> lane holds 4 consecutive n (packed C store).
// SWAP=true:  acc = mfma(a,b) -> lane holds 4 consecutive m (packed V^T store).
template <bool SWAP>
DEV void mfma_step(const u16* As, const u16* Bs, int lane, int wv, floatx4 acc[4][4]) {
  const int wr = wv >> 1, wc = wv & 1;
  const int r16 = lane & 15, q4 = lane >> 4;
  const int base = (r16 >> 1) * 64 + (((r16 & 1) * 4 + q4) ^ ((r16 >> 1) & 7)) * 8;
  short8 a[4], b[4];
#pragma unroll
  for (int i = 0; i < 4; ++i) {
    a[i] = *(const short8*)(As + wr * 2048 + i * 512 + base);
    b[i] = *(const short8*)(Bs + wc * 2048 + i * 512 + base);
  }
#pragma unroll
  for (int i = 0; i < 4; ++i)
#pragma unroll
    for (int j = 0; j < 4; ++j)
      acc[i][j] = SWAP
          ? __builtin_amdgcn_mfma_f32_16x16x32_bf16(a[i], b[j], acc[i][j], 0, 0, 0)
          : __builtin_amdgcn_mfma_f32_16x16x32_bf16(b[j], a[i], acc[i][j], 0, 0, 0);
}

// Depth-2 pipelined K-loop (T3+T4): 3 LDS buffers, raw s_barrier (NO vmcnt
// drain), counted s_waitcnt vmcnt(4) -- 8 DMAs/thread stay in flight across
// barriers. Staging for ks+2 is issued AFTER the barrier: all waves finished
// reading buf[(ks+2)%3] (= buf[(ks-1)%3]) in compute(ks-1) before arriving,
// so the overwrite is WAR-safe. compute(ks)'s own data is guaranteed by
// vmcnt<=4 (only ks+1's 4 DMAs may remain) + the barrier (every wave made
// the same guarantee for its own stores before crossing).
template <bool SWAP>
DEV void gemm_loop128(const u16* Ab, const u16* Wb, u16 (*As)[4096], u16 (*Bs)[4096],
                      int tid, floatx4 acc[4][4]) {
  const int lane = tid & 63, wv = tid >> 6;
  stage_tile(Ab, As[0], tid);
  stage_tile(Wb, Bs[0], tid);
  stage_tile(Ab + 32, As[1], tid);
  stage_tile(Wb + 32, Bs[1], tid);
#pragma unroll
  for (int ks = 0; ks < 8; ++ks) {
    if (ks < 7) asm volatile("s_waitcnt vmcnt(4)" ::: "memory");
    else        asm volatile("s_waitcnt vmcnt(0)" ::: "memory");
    asm volatile("s_barrier" ::: "memory");
    if (ks < 6) {
      stage_tile(Ab + (ks + 2) * 32, As[(ks + 2) % 3], tid);
      stage_tile(Wb + (ks + 2) * 32, Bs[(ks + 2) % 3], tid);
    }
    mfma_step<SWAP>(As[ks % 3], Bs[ks % 3], lane, wv, acc);
  }
}

// ------------------------------------------------------------ QKV GEMM
// z=0: Q (pre-scaled by QSC), z=1: K, z=2: V^T (SWAP'd loop, permuted cols).
__global__ __launch_bounds__(256) void gemm_qkv_kernel(
    const u16* __restrict__ A, const u16* __restrict__ wb,
    u16* __restrict__ C0, u16* __restrict__ C1,
    u16* __restrict__ VT, int mstride) {
  alignas(16) __shared__ u16 As[3][128 * 32];
  alignas(16) __shared__ u16 Bs[3][128 * 32];
  const int tid = threadIdx.x, lane = tid & 63, wv = tid >> 6;
  const int m0 = blockIdx.x * 128, n0 = blockIdx.y * 128;
  const int bz = blockIdx.z;
  const u16* Wp = wb + (size_t)bz * 65536;
  const int wr = wv >> 1, wc = wv & 1, q4 = lane >> 4, r16 = lane & 15;

  floatx4 acc[4][4] = {};
  if (bz == 2) {
    // V^T path (round-4 verified): lane reg r = C[m=mb+q4*4+r][n=d];
    // store V^T[d][pcol(m)], pcol bakes in the PV k-window permutation.
    gemm_loop128<true>(A + (size_t)m0 * 256, Wp + (size_t)n0 * 256, As, Bs, tid, acc);
#pragma unroll
    for (int i = 0; i < 4; ++i) {
      const int mb = m0 + wr * 64 + i * 16;  // 16-aligned
      const int pc = (mb & ~31) + q4 * 8 + ((mb >> 4) & 1) * 4;
#pragma unroll
      for (int j = 0; j < 4; ++j) {
        const int d = n0 + wc * 64 + j * 16 + r16;
        uint2_ma o;
        o.x = pkbf(acc[i][j][0], acc[i][j][1]);
        o.y = pkbf(acc[i][j][2], acc[i][j][3]);
        *(uint2_ma*)(VT + (size_t)d * mstride + pc) = o;
      }
    }
  } else {
    gemm_loop128<false>(A + (size_t)m0 * 256, Wp + (size_t)n0 * 256, As, Bs, tid, acc);
    u16* Cp = (bz == 0) ? C0 : C1;
    const float qs = (bz == 0) ? QSC : 1.0f;
#pragma unroll
    for (int i = 0; i < 4; ++i) {
      const int m = m0 + wr * 64 + i * 16 + r16;
#pragma unroll
      for (int j = 0; j < 4; ++j) {
        const int n = n0 + wc * 64 + j * 16 + q4 * 4;
        uint2_ma o;
        o.x = pkbf(acc[i][j][0] * qs, acc[i][j][1] * qs);
        o.y = pkbf(acc[i][j][2] * qs, acc[i][j][3] * qs);
        *(uint2_ma*)(Cp + (size_t)m * 256 + n) = o;
      }
    }
  }
}

// ------------------------------------------------------------ out-proj GEMM
__global__ __launch_bounds__(256) void gemm_out_kernel(
    const u16* __restrict__ AO, const u16* __restrict__ WOb,
    const float* __restrict__ bo, float* __restrict__ OUT) {
  alignas(16) __shared__ u16 As[3][128 * 32];
  alignas(16) __shared__ u16 Bs[3][128 * 32];
  const int tid = threadIdx.x, lane = tid & 63, wv = tid >> 6;
  const int m0 = blockIdx.x * 128, n0 = blockIdx.y * 128;

  floatx4 acc[4][4] = {};
  gemm_loop128<false>(AO + (size_t)m0 * 256, WOb + (size_t)n0 * 256, As, Bs, tid, acc);

  const int wr = wv >> 1, wc = wv & 1, q4 = lane >> 4, r16 = lane & 15;
#pragma unroll
  for (int i = 0; i < 4; ++i) {
    const int m = m0 + wr * 64 + i * 16 + r16;
#pragma unroll
    for (int j = 0; j < 4; ++j) {
      const int n = n0 + wc * 64 + j * 16 + q4 * 4;
      floatx4_ma bv = *(const floatx4_ma*)(bo + n);
      floatx4_ma o;
      o[0] = acc[i][j][0] + bv[0];
      o[1] = acc[i][j][1] + bv[1];
      o[2] = acc[i][j][2] + bv[2];
      o[3] = acc[i][j][3] + bv[3];
      *(floatx4_ma*)(OUT + (size_t)m * 256 + n) = o;
    }
  }
}

// ------------------------------------------------------------ row attention
// ROUND-4-VERIFIED STRUCTURE. Only change: Q arrives pre-scaled by QSC, so
// softmax is p = exp2(sc - mx) -- 2 VALU/elem instead of 4.
__global__ __launch_bounds__(256) void attn_kernel(
    const u16* __restrict__ Q, const u16* __restrict__ K,
    const u16* __restrict__ VT, u16* __restrict__ O, int mstride) {
  alignas(16) __shared__ u16 Ksh[2][4096];   // 16 KiB, paired-line swizzle
  alignas(16) __shared__ u16 Vlds[32 * 256]; // 16 KiB, granule-XOR swizzle
  const int h = blockIdx.x;
  const int s = blockIdx.y;
  const int tid = threadIdx.x;
  const int lane = tid & 63;
  const int wv = tid >> 6;
  const int q4 = lane >> 4, r16 = lane & 15;
  const size_t rowbase = (size_t)s * 256;

  // stage K rows 0..255 (head slice) via the GEMM-verified path
  stage_tile(K + rowbase * 256 + h * 32, Ksh[0], tid);
  stage_tile(K + (rowbase + 128) * 256 + h * 32, Ksh[1], tid);
  {  // stage V^T: slot (d, g') <- source granule g = (g'&24)|((g'^d)&7)
    const u16* vsrc = VT + (size_t)(h * 32) * mstride + rowbase;
#pragma unroll
    for (int it = 0; it < 4; ++it) {
      const int slot = it * 256 + tid;
      const int d = slot >> 5, gp = slot & 31;
      const int g = (gp & 24) | ((gp ^ d) & 7);
      __builtin_amdgcn_global_load_lds(
          (const __attribute__((address_space(1))) u32*)(vsrc + (size_t)d * mstride + g * 8),
          (__attribute__((address_space(3))) u32*)(Vlds + (it * 256 + (tid & ~63)) * 8),
          16, 0, 0);
    }
  }
  // Q prefetch (latency hides under the staging barrier)
  short8 aq[4];
#pragma unroll
  for (int mt0 = 0; mt0 < 4; ++mt0)
    aq[mt0] = *(const short8*)(Q + (rowbase + (mt0 * 4 + wv) * 16 + r16) * 256 + h * 32 + q4 * 8);
  __syncthreads();  // drains vmcnt (DMA) before any wave proceeds

  // lane-constant K fragment base (row = t*16 + r16, granule = q4)
  const int kbase = (r16 >> 1) * 64 + ((((r16 & 1) * 4 + q4) ^ ((r16 >> 1) & 7)) << 3);

#pragma unroll
  for (int mt0 = 0; mt0 < 4; ++mt0) {
    const int qbase = (mt0 * 4 + wv) * 16;
    // sc[t][r] = S_scaled[k = t*16 + q4*4 + r][q = qbase + r16]
    floatx4 sc[16];
#pragma unroll
    for (int t = 0; t < 16; ++t) {
      const short8 bk = *(const short8*)(&Ksh[t >> 3][(t & 7) * 512 + kbase]);
      floatx4 z = {0.f, 0.f, 0.f, 0.f};
      sc[t] = __builtin_amdgcn_mfma_f32_16x16x32_bf16(bk, aq[mt0], z, 0, 0, 0);
    }
    // lane-local softmax for q = qbase + r16 (combine q4-peers via xor16/32)
    float mx = -3.0e38f;
#pragma unroll
    for (int t = 0; t < 16; ++t)
      mx = fmaxf(mx, fmaxf(fmaxf(sc[t][0], sc[t][1]), fmaxf(sc[t][2], sc[t][3])));
    mx = fmaxf(mx, __shfl_xor(mx, 16, 64));
    mx = fmaxf(mx, __shfl_xor(mx, 32, 64));
    float sum = 0.f;
#pragma unroll
    for (int t = 0; t < 16; ++t) {
#pragma unroll
      for (int r = 0; r < 4; ++r) {
        const float p = exp2g(sc[t][r] - mx);  // = e^{ATT_SCALE*(score-max)}
        sc[t][r] = p;
        sum += p;
      }
    }
    sum += __shfl_xor(sum, 16, 64);
    sum += __shfl_xor(sum, 32, 64);
    const float inv = 1.0f / sum;

    // PV: P operand = own registers (permuted window), V = 2x ds_read_b128.
    floatx4 o0 = {0.f, 0.f, 0.f, 0.f}, o1 = {0.f, 0.f, 0.f, 0.f};
#pragma unroll
    for (int kk = 0; kk < 8; ++kk) {
      const int gv = kk * 4 + q4;
      const int goff = ((gv & 24) | ((gv ^ (r16 & 7)) & 7)) << 3;
      const short8 bv0 = *(const short8*)(Vlds + r16 * 256 + goff);
      const short8 bv1 = *(const short8*)(Vlds + (16 + r16) * 256 + goff);
      P8 ap;  // slots: e<4 -> sc[2kk][e] (k=32kk+q4*4+e); e>=4 -> sc[2kk+1]
      ap.w[0] = pkbf(sc[2 * kk][0], sc[2 * kk][1]);
      ap.w[1] = pkbf(sc[2 * kk][2], sc[2 * kk][3]);
      ap.w[2] = pkbf(sc[2 * kk + 1][0], sc[2 * kk + 1][1]);
      ap.w[3] = pkbf(sc[2 * kk + 1][2], sc[2 * kk + 1][3]);
      o0 = __builtin_amdgcn_mfma_f32_16x16x32_bf16(bv0, ap.v, o0, 0, 0, 0);
      o1 = __builtin_amdgcn_mfma_f32_16x16x32_bf16(bv1, ap.v, o1, 0, 0, 0);
    }
    // o0[r] = out[d = q4*4+r][q = r16]; o1 -> d+16. Packed 8B stores.
    const size_t ob = (rowbase + qbase + r16) * 256 + h * 32;
    uint2_ma w0, w1;
    w0.x = pkbf(o0[0] * inv, o0[1] * inv);
    w0.y = pkbf(o0[2] * inv, o0[3] * inv);
    w1.x = pkbf(o1[0] * inv, o1[1] * inv);
    w1.y = pkbf(o1[2] * inv, o1[3] * inv);
    *(uint2_ma*)(O + ob + q4 * 4) = w0;
    *(uint2_ma*)(O + ob + 16 + q4 * 4) = w1;
  }
}

// ---------------------------------------------------------------- launch
extern "C" void kernel_launch(void* const* d_in, const int* in_sizes, int n_in,
                              void* d_out, int out_size, void* d_ws, size_t ws_size,
                              hipStream_t stream) {
  (void)in_sizes; (void)n_in; (void)out_size;
  const float* msa = (const float*)d_in[0];
  const float* lnw = (const float*)d_in[1];
  const float* lnb = (const float*)d_in[2];
  const float* wq = (const float*)d_in[3];
  const float* wk = (const float*)d_in[4];
  const float* wvp = (const float*)d_in[5];
  const float* wo = (const float*)d_in[6];
  const float* bo = (const float*)d_in[7];
  float* out = (float*)d_out;

  // ws layout: wb (4 x 256x256 bf16 weights, 512 KiB) | per-chunk xn,q,k,vT.
  u16* wb = (u16*)d_ws;
  u16* xnc = wb + 4 * 65536;
  const size_t avail = (ws_size > 524288ull) ? ws_size - 524288ull : 0;
  int CS = S;  // s-rows per chunk, pow2
  while (CS > 1 && (size_t)CS * 524288ull > avail) CS >>= 1;
  const int nch = S / CS;
  const size_t chunkElems = (size_t)CS * NRES * D;  // per tensor
  u16* qc = xnc + chunkElems;
  u16* kc = qc + chunkElems;
  u16* vtc = kc + chunkElems;  // V^T [256 d][mrows], permuted cols
  u16* aoc = xnc;              // xn dead after QKV GEMM

  wcvt_kernel<<<dim3(32, 4), 256, 0, stream>>>(wq, wk, wvp, wo, wb);

  const int mrows = CS * NRES;  // rows per chunk
  for (int c = 0; c < nch; ++c) {
    const size_t row0 = (size_t)c * mrows;
    ln_kernel<<<mrows / 4, 256, 0, stream>>>(msa + row0 * D, lnw, lnb, xnc);
    gemm_qkv_kernel<<<dim3(mrows / 128, 2, 3), 256, 0, stream>>>(xnc, wb, qc, kc, vtc, mrows);
    attn_kernel<<<dim3(H, CS), 256, 0, stream>>>(qc, kc, vtc, aoc, mrows);
    gemm_out_kernel<<<dim3(mrows / 128, 2), 256, 0, stream>>>(aoc, wb + 3 * 65536, bo, out + row0 * D);
  }
}

// Round 8
// 160.894 us; speedup vs baseline: 1.2032x; 1.0084x over previous
//
#include <hip/hip_runtime.h>

typedef unsigned short u16;
typedef unsigned int u32;
// may_alias: reinterpret-cast LDS/global vector access (prevent TBAA reorder).
typedef __attribute__((ext_vector_type(8), may_alias)) short short8;
typedef __attribute__((ext_vector_type(4), may_alias)) u32 uint4_ma;
typedef __attribute__((ext_vector_type(2), may_alias)) u32 uint2_ma;
typedef __attribute__((ext_vector_type(4), may_alias)) float floatx4_ma;
typedef __attribute__((ext_vector_type(4))) float floatx4;

#define DEV static __device__ __forceinline__

constexpr int S = 128, NRES = 256, D = 256, H = 8;
// Q is pre-scaled by ATT_SCALE*log2(e) in the QKV epilogue, so softmax is
// p = exp2(sc - mx) exactly: e^{ATT_SCALE*(score-max)}.
constexpr float QSC = 0.25503486f;  // (1/sqrt(32)) * log2(e)

// v_cvt_pk_bf16_f32: lo16 = bf16(a), hi16 = bf16(b). VERIFIED round 3.
DEV u32 pkbf(float a, float b) {
  u32 r;
  asm("v_cvt_pk_bf16_f32 %0, %1, %2" : "=v"(r) : "v"(a), "v"(b));
  return r;
}

#if __has_builtin(__builtin_amdgcn_exp2f)
DEV float exp2g(float x) { return __builtin_amdgcn_exp2f(x); }
#else
DEV float exp2g(float x) { return __expf(x * 0.6931471805599453f); }
#endif

union P8 { u32 w[4]; short8 v; };

// ---------------------------------------------------------------- LayerNorm
// f32 in, bf16 out. One wave per row of 256; float4/lane. ~BW roofline.
// (round-5-verified standalone; the round-6/7 wcvt merge is REVERTED --
// it is in the failure-suspect set.)
__global__ __launch_bounds__(256) void ln_kernel(const float* __restrict__ x,
                                                 const float* __restrict__ w,
                                                 const float* __restrict__ b,
                                                 u16* __restrict__ xn) {
  const int lane = threadIdx.x & 63;
  const int row = blockIdx.x * 4 + (threadIdx.x >> 6);
  floatx4_ma d = ((const floatx4_ma*)(x + (size_t)row * D))[lane];
  float s = d[0] + d[1] + d[2] + d[3];
  float ss = d[0] * d[0] + d[1] * d[1] + d[2] * d[2] + d[3] * d[3];
#pragma unroll
  for (int off = 32; off > 0; off >>= 1) {
    s += __shfl_xor(s, off, 64);
    ss += __shfl_xor(ss, off, 64);
  }
  const float mean = s * (1.0f / D);
  const float var = ss * (1.0f / D) - mean * mean;
  const float rstd = rsqrtf(var + 1e-5f);
  floatx4_ma wd = ((const floatx4_ma*)w)[lane];
  floatx4_ma bd = ((const floatx4_ma*)b)[lane];
  uint2_ma o;
  o.x = pkbf((d[0] - mean) * rstd * wd[0] + bd[0],
             (d[1] - mean) * rstd * wd[1] + bd[1]);
  o.y = pkbf((d[2] - mean) * rstd * wd[2] + bd[2],
             (d[3] - mean) * rstd * wd[3] + bd[3]);
  ((uint2_ma*)(xn + (size_t)row * D))[lane] = o;
}

// ------------------------------------------------- weight pre-conversion
// Standalone (round-5-verified).
__global__ __launch_bounds__(256) void wcvt_kernel(
    const float* __restrict__ w0, const float* __restrict__ w1,
    const float* __restrict__ w2, const float* __restrict__ w3,
    u16* __restrict__ wb) {
  const float* src = (blockIdx.y == 0) ? w0
                     : ((blockIdx.y == 1) ? w1 : ((blockIdx.y == 2) ? w2 : w3));
  u16* dst = wb + (size_t)blockIdx.y * 65536;
  const int i = (blockIdx.x * 256 + threadIdx.x) * 8;
  floatx4_ma f0 = *(const floatx4_ma*)(src + i);
  floatx4_ma f1 = *(const floatx4_ma*)(src + i + 4);
  uint4_ma hv;
  hv.x = pkbf(f0[0], f0[1]);
  hv.y = pkbf(f0[2], f0[3]);
  hv.z = pkbf(f1[0], f1[1]);
  hv.w = pkbf(f1[2], f1[3]);
  *(uint4_ma*)(dst + i) = hv;
}

// ------------------------------------------------------- GEMM staging
// 128x32 bf16 tile, pure global_load_lds DMA. LDS paired-line layout:
// elem (row,g) at line=row>>1, pos=((row&1)*4+g)^(line&7): u16 line*64+pos*8.
// Per-phase ds_read_b128 is 2-way max (free). Source is inverse-swizzled.
// VERIFIED (rounds 3/4/5 pass).
DEV void stage_tile(const u16* src, u16* dst, int tid) {
  const int pos = tid & 7;
  const int l0 = tid >> 3;              // line within it=0 half (0..31)
  const int pre = pos ^ (l0 & 7);
  const int row0 = l0 * 2 + (pre >> 2);
  const int g = pre & 3;
#pragma unroll
  for (int it = 0; it < 2; ++it) {
    __builtin_amdgcn_global_load_lds(
        (const __attribute__((address_space(1))) u32*)(src + (row0 + it * 64) * 256 + g * 8),
        (__attribute__((address_space(3))) u32*)(dst + (it * 256 + (tid & ~63)) * 8),
        16, 0, 0);
  }
}

// One BK=32 step: 8 ds_read_b128 + 16 MFMA per wave. VERIFIED (rounds 3/4/5).
// SWAP=false: acc = mfma(b,a) -> lane holds 4 consecutive n (packed C store).
// SWAP=true:  acc = mfma(a,b) -> lane holds 4 consecutive m (packed V^T store).
// NEW (T5, zero correctness risk): s_setprio(1) around the MFMA cluster.
template <bool SWAP>
DEV void mfma_step(const u16* As, const u16* Bs, int lane, int wv, floatx4 acc[4][4]) {
  const int wr = wv >> 1, wc = wv & 1;
  const int r16 = lane & 15, q4 = lane >> 4;
  const int base = (r16 >> 1) * 64 + (((r16 & 1) * 4 + q4) ^ ((r16 >> 1) & 7)) * 8;
  short8 a[4], b[4];
#pragma unroll
  for (int i = 0; i < 4; ++i) {
    a[i] = *(const short8*)(As + wr * 2048 + i * 512 + base);
    b[i] = *(const short8*)(Bs + wc * 2048 + i * 512 + base);
  }
  __builtin_amdgcn_s_setprio(1);
#pragma unroll
  for (int i = 0; i < 4; ++i)
#pragma unroll
    for (int j = 0; j < 4; ++j)
      acc[i][j] = SWAP
          ? __builtin_amdgcn_mfma_f32_16x16x32_bf16(a[i], b[j], acc[i][j], 0, 0, 0)
          : __builtin_amdgcn_mfma_f32_16x16x32_bf16(b[j], a[i], acc[i][j], 0, 0, 0);
  __builtin_amdgcn_s_setprio(0);
}

// Depth-2 pipelined K-loop (T3+T4), VERIFIED round 5: 3 LDS buffers, raw
// s_barrier, counted s_waitcnt vmcnt(4) -- 8 DMAs/thread in flight across
// barriers; stage(ks+2) issued AFTER the barrier (WAR-safe). Sound because
// ALL counted ops are global_load_lds builtins in fixed program order.
template <bool SWAP>
DEV void gemm_loop128(const u16* Ab, const u16* Wb, u16 (*As)[4096], u16 (*Bs)[4096],
                      int tid, floatx4 acc[4][4]) {
  const int lane = tid & 63, wv = tid >> 6;
  stage_tile(Ab, As[0], tid);
  stage_tile(Wb, Bs[0], tid);
  stage_tile(Ab + 32, As[1], tid);
  stage_tile(Wb + 32, Bs[1], tid);
#pragma unroll
  for (int ks = 0; ks < 8; ++ks) {
    if (ks < 7) asm volatile("s_waitcnt vmcnt(4)" ::: "memory");
    else        asm volatile("s_waitcnt vmcnt(0)" ::: "memory");
    asm volatile("s_barrier" ::: "memory");
    if (ks < 6) {
      stage_tile(Ab + (ks + 2) * 32, As[(ks + 2) % 3], tid);
      stage_tile(Wb + (ks + 2) * 32, Bs[(ks + 2) % 3], tid);
    }
    mfma_step<SWAP>(As[ks % 3], Bs[ks % 3], lane, wv, acc);
  }
}

// ------------------------------------------------------------ QKV GEMM
// z=0: Q (pre-scaled by QSC), z=1: K, z=2: V^T (SWAP'd loop, permuted cols,
// DIRECT scatter store -- the round-5-verified epilogue; the round-6/7 LDS
// transpose is REVERTED as the prime failure suspect).
__global__ __launch_bounds__(256) void gemm_qkv_kernel(
    const u16* __restrict__ A, const u16* __restrict__ wb,
    u16* __restrict__ C0, u16* __restrict__ C1,
    u16* __restrict__ VT, int mstride) {
  alignas(16) __shared__ u16 As[3][128 * 32];
  alignas(16) __shared__ u16 Bs[3][128 * 32];
  const int tid = threadIdx.x, lane = tid & 63, wv = tid >> 6;
  const int m0 = blockIdx.x * 128, n0 = blockIdx.y * 128;
  const int bz = blockIdx.z;
  const u16* Wp = wb + (size_t)bz * 65536;
  const int wr = wv >> 1, wc = wv & 1, q4 = lane >> 4, r16 = lane & 15;

  floatx4 acc[4][4] = {};
  if (bz == 2) {
    // V^T path (rounds 4/5 verified): lane reg r = C[m=mb+q4*4+r][n=d];
    // store VT[d][pcol(m)], pcol bakes in the PV k-window permutation.
    gemm_loop128<true>(A + (size_t)m0 * 256, Wp + (size_t)n0 * 256, As, Bs, tid, acc);
#pragma unroll
    for (int i = 0; i < 4; ++i) {
      const int mb = m0 + wr * 64 + i * 16;  // 16-aligned
      const int pc = (mb & ~31) + q4 * 8 + ((mb >> 4) & 1) * 4;
#pragma unroll
      for (int j = 0; j < 4; ++j) {
        const int d = n0 + wc * 64 + j * 16 + r16;
        uint2_ma o;
        o.x = pkbf(acc[i][j][0], acc[i][j][1]);
        o.y = pkbf(acc[i][j][2], acc[i][j][3]);
        *(uint2_ma*)(VT + (size_t)d * mstride + pc) = o;
      }
    }
  } else {
    gemm_loop128<false>(A + (size_t)m0 * 256, Wp + (size_t)n0 * 256, As, Bs, tid, acc);
    u16* Cp = (bz == 0) ? C0 : C1;
    const float qs = (bz == 0) ? QSC : 1.0f;
#pragma unroll
    for (int i = 0; i < 4; ++i) {
      const int m = m0 + wr * 64 + i * 16 + r16;
#pragma unroll
      for (int j = 0; j < 4; ++j) {
        const int n = n0 + wc * 64 + j * 16 + q4 * 4;
        uint2_ma o;
        o.x = pkbf(acc[i][j][0] * qs, acc[i][j][1] * qs);
        o.y = pkbf(acc[i][j][2] * qs, acc[i][j][3] * qs);
        *(uint2_ma*)(Cp + (size_t)m * 256 + n) = o;
      }
    }
  }
}

// ------------------------------------------------------------ out-proj GEMM
__global__ __launch_bounds__(256) void gemm_out_kernel(
    const u16* __restrict__ AO, const u16* __restrict__ WOb,
    const float* __restrict__ bo, float* __restrict__ OUT) {
  alignas(16) __shared__ u16 As[3][128 * 32];
  alignas(16) __shared__ u16 Bs[3][128 * 32];
  const int tid = threadIdx.x, lane = tid & 63, wv = tid >> 6;
  const int m0 = blockIdx.x * 128, n0 = blockIdx.y * 128;

  floatx4 acc[4][4] = {};
  gemm_loop128<false>(AO + (size_t)m0 * 256, WOb + (size_t)n0 * 256, As, Bs, tid, acc);

  const int wr = wv >> 1, wc = wv & 1, q4 = lane >> 4, r16 = lane & 15;
#pragma unroll
  for (int i = 0; i < 4; ++i) {
    const int m = m0 + wr * 64 + i * 16 + r16;
#pragma unroll
    for (int j = 0; j < 4; ++j) {
      const int n = n0 + wc * 64 + j * 16 + q4 * 4;
      floatx4_ma bv = *(const floatx4_ma*)(bo + n);
      floatx4_ma o;
      o[0] = acc[i][j][0] + bv[0];
      o[1] = acc[i][j][1] + bv[1];
      o[2] = acc[i][j][2] + bv[2];
      o[3] = acc[i][j][3] + bv[3];
      *(floatx4_ma*)(OUT + (size_t)m * 256 + n) = o;
    }
  }
}

// ------------------------------------------------------------ row attention
// ROUND-5-VERIFIED VERSION. Single __syncthreads full drain after staging.
// Only addition: T5 s_setprio around the QK^T and PV MFMA clusters.
__global__ __launch_bounds__(256) void attn_kernel(
    const u16* __restrict__ Q, const u16* __restrict__ K,
    const u16* __restrict__ VT, u16* __restrict__ O, int mstride) {
  alignas(16) __shared__ u16 Ksh[2][4096];   // 16 KiB, paired-line swizzle
  alignas(16) __shared__ u16 Vlds[32 * 256]; // 16 KiB, granule-XOR swizzle
  const int h = blockIdx.x;
  const int s = blockIdx.y;
  const int tid = threadIdx.x;
  const int lane = tid & 63;
  const int wv = tid >> 6;
  const int q4 = lane >> 4, r16 = lane & 15;
  const size_t rowbase = (size_t)s * 256;

  // stage K rows 0..255 (head slice) via the GEMM-verified path
  stage_tile(K + rowbase * 256 + h * 32, Ksh[0], tid);
  stage_tile(K + (rowbase + 128) * 256 + h * 32, Ksh[1], tid);
  {  // stage V^T: slot (d, g') <- source granule g = (g'&24)|((g'^d)&7)
    const u16* vsrc = VT + (size_t)(h * 32) * mstride + rowbase;
#pragma unroll
    for (int it = 0; it < 4; ++it) {
      const int slot = it * 256 + tid;
      const int d = slot >> 5, gp = slot & 31;
      const int g = (gp & 24) | ((gp ^ d) & 7);
      __builtin_amdgcn_global_load_lds(
          (const __attribute__((address_space(1))) u32*)(vsrc + (size_t)d * mstride + g * 8),
          (__attribute__((address_space(3))) u32*)(Vlds + (it * 256 + (tid & ~63)) * 8),
          16, 0, 0);
    }
  }
  // Q prefetch (latency hides under the staging barrier)
  short8 aq[4];
#pragma unroll
  for (int mt0 = 0; mt0 < 4; ++mt0)
    aq[mt0] = *(const short8*)(Q + (rowbase + (mt0 * 4 + wv) * 16 + r16) * 256 + h * 32 + q4 * 8);
  __syncthreads();  // drains vmcnt (DMA) before any wave proceeds

  // lane-constant K fragment base (row = t*16 + r16, granule = q4)
  const int kbase = (r16 >> 1) * 64 + ((((r16 & 1) * 4 + q4) ^ ((r16 >> 1) & 7)) << 3);

#pragma unroll
  for (int mt0 = 0; mt0 < 4; ++mt0) {
    const int qbase = (mt0 * 4 + wv) * 16;
    // sc[t][r] = S_scaled[k = t*16 + q4*4 + r][q = qbase + r16]
    floatx4 sc[16];
    __builtin_amdgcn_s_setprio(1);
#pragma unroll
    for (int t = 0; t < 16; ++t) {
      const short8 bk = *(const short8*)(&Ksh[t >> 3][(t & 7) * 512 + kbase]);
      floatx4 z = {0.f, 0.f, 0.f, 0.f};
      sc[t] = __builtin_amdgcn_mfma_f32_16x16x32_bf16(bk, aq[mt0], z, 0, 0, 0);
    }
    __builtin_amdgcn_s_setprio(0);
    // lane-local softmax for q = qbase + r16 (combine q4-peers via xor16/32)
    float mx = -3.0e38f;
#pragma unroll
    for (int t = 0; t < 16; ++t)
      mx = fmaxf(mx, fmaxf(fmaxf(sc[t][0], sc[t][1]), fmaxf(sc[t][2], sc[t][3])));
    mx = fmaxf(mx, __shfl_xor(mx, 16, 64));
    mx = fmaxf(mx, __shfl_xor(mx, 32, 64));
    float sum = 0.f;
#pragma unroll
    for (int t = 0; t < 16; ++t) {
#pragma unroll
      for (int r = 0; r < 4; ++r) {
        const float p = exp2g(sc[t][r] - mx);  // = e^{ATT_SCALE*(score-max)}
        sc[t][r] = p;
        sum += p;
      }
    }
    sum += __shfl_xor(sum, 16, 64);
    sum += __shfl_xor(sum, 32, 64);
    const float inv = 1.0f / sum;

    // PV: P operand = own registers (permuted window), V = 2x ds_read_b128.
    floatx4 o0 = {0.f, 0.f, 0.f, 0.f}, o1 = {0.f, 0.f, 0.f, 0.f};
    __builtin_amdgcn_s_setprio(1);
#pragma unroll
    for (int kk = 0; kk < 8; ++kk) {
      const int gv = kk * 4 + q4;
      const int goff = ((gv & 24) | ((gv ^ (r16 & 7)) & 7)) << 3;
      const short8 bv0 = *(const short8*)(Vlds + r16 * 256 + goff);
      const short8 bv1 = *(const short8*)(Vlds + (16 + r16) * 256 + goff);
      P8 ap;  // slots: e<4 -> sc[2kk][e] (k=32kk+q4*4+e); e>=4 -> sc[2kk+1]
      ap.w[0] = pkbf(sc[2 * kk][0], sc[2 * kk][1]);
      ap.w[1] = pkbf(sc[2 * kk][2], sc[2 * kk][3]);
      ap.w[2] = pkbf(sc[2 * kk + 1][0], sc[2 * kk + 1][1]);
      ap.w[3] = pkbf(sc[2 * kk + 1][2], sc[2 * kk + 1][3]);
      o0 = __builtin_amdgcn_mfma_f32_16x16x32_bf16(bv0, ap.v, o0, 0, 0, 0);
      o1 = __builtin_amdgcn_mfma_f32_16x16x32_bf16(bv1, ap.v, o1, 0, 0, 0);
    }
    __builtin_amdgcn_s_setprio(0);
    // o0[r] = out[d = q4*4+r][q = r16]; o1 -> d+16. Packed 8B stores.
    const size_t ob = (rowbase + qbase + r16) * 256 + h * 32;
    uint2_ma w0, w1;
    w0.x = pkbf(o0[0] * inv, o0[1] * inv);
    w0.y = pkbf(o0[2] * inv, o0[3] * inv);
    w1.x = pkbf(o1[0] * inv, o1[1] * inv);
    w1.y = pkbf(o1[2] * inv, o1[3] * inv);
    *(uint2_ma*)(O + ob + q4 * 4) = w0;
    *(uint2_ma*)(O + ob + 16 + q4 * 4) = w1;
  }
}

// ---------------------------------------------------------------- launch
extern "C" void kernel_launch(void* const* d_in, const int* in_sizes, int n_in,
                              void* d_out, int out_size, void* d_ws, size_t ws_size,
                              hipStream_t stream) {
  (void)in_sizes; (void)n_in; (void)out_size;
  const float* msa = (const float*)d_in[0];
  const float* lnw = (const float*)d_in[1];
  const float* lnb = (const float*)d_in[2];
  const float* wq = (const float*)d_in[3];
  const float* wk = (const float*)d_in[4];
  const float* wvp = (const float*)d_in[5];
  const float* wo = (const float*)d_in[6];
  const float* bo = (const float*)d_in[7];
  float* out = (float*)d_out;

  // ws layout: wb (4 x 256x256 bf16 weights, 512 KiB) | per-chunk xn,q,k,vT.
  u16* wb = (u16*)d_ws;
  u16* xnc = wb + 4 * 65536;
  const size_t avail = (ws_size > 524288ull) ? ws_size - 524288ull : 0;
  int CS = S;  // s-rows per chunk, pow2
  while (CS > 1 && (size_t)CS * 524288ull > avail) CS >>= 1;
  const int nch = S / CS;
  const size_t chunkElems = (size_t)CS * NRES * D;  // per tensor
  u16* qc = xnc + chunkElems;
  u16* kc = qc + chunkElems;
  u16* vtc = kc + chunkElems;  // V^T [256 d][mrows], permuted cols
  u16* aoc = xnc;              // xn dead after QKV GEMM

  wcvt_kernel<<<dim3(32, 4), 256, 0, stream>>>(wq, wk, wvp, wo, wb);

  const int mrows = CS * NRES;  // rows per chunk
  for (int c = 0; c < nch; ++c) {
    const size_t row0 = (size_t)c * mrows;
    ln_kernel<<<mrows / 4, 256, 0, stream>>>(msa + row0 * D, lnw, lnb, xnc);
    gemm_qkv_kernel<<<dim3(mrows / 128, 2, 3), 256, 0, stream>>>(xnc, wb, qc, kc, vtc, mrows);
    attn_kernel<<<dim3(H, CS), 256, 0, stream>>>(qc, kc, vtc, aoc, mrows);
    gemm_out_kernel<<<dim3(mrows / 128, 2), 256, 0, stream>>>(aoc, wb + 3 * 65536, bo, out + row0 * D);
  }
}